// Round 12
// baseline (563.865 us; speedup 1.0000x reference)
//
#include <hip/hip_runtime.h>

typedef unsigned short u16;
typedef unsigned int   u32;
typedef unsigned long long u64;
typedef __attribute__((ext_vector_type(8))) short bf16x8;
typedef __attribute__((ext_vector_type(8))) unsigned short u16x8;
typedef __attribute__((ext_vector_type(4))) float f32x4;

__device__ __forceinline__ float bf2f(u16 h){ u32 u = ((u32)h)<<16; return __builtin_bit_cast(float, u); }
__device__ __forceinline__ u16 f2bf(float f){
    u32 u = __builtin_bit_cast(u32, f);
    return (u16)((u + 0x7FFFu + ((u>>16)&1u)) >> 16);   // RNE
}
__device__ __forceinline__ u16 ftrunc_bf(float f){      // exact for bf16-valued f32
    return (u16)(__builtin_bit_cast(u32, f) >> 16);
}

__device__ __forceinline__ void gload16(const void* g, void* l){
    __builtin_amdgcn_global_load_lds((const __attribute__((address_space(1))) void*)g,
                                     (__attribute__((address_space(3))) void*)l, 16, 0, 0);
}

// st_16x32 swizzle on byte offsets: XOR bit9 into bit5 (involution; row bits untouched)
__device__ __forceinline__ int swz(int o){ return o ^ (((o >> 9) & 1) << 5); }

// ===================== 8-phase-style 256x256 GEMM (mk only) =================
// C[4096][4096] = A[4096][4096(K)] @ B[4096][4096(K)]^T, bf16, scale=1.
// 512 thr = 8 waves (2M x 4N), BK=64, dbuf 128KiB dynamic LDS, counted vmcnt(8),
// raw s_barrier, T2 swizzle both-sides, setprio around MFMA cluster.
__global__ __launch_bounds__(512, 2) void gemm8ph(
    const u16* __restrict__ A, const u16* __restrict__ B, u16* __restrict__ C)
{
    extern __shared__ u16 lds[];   // [2 buf][2 mat][16384 elems] = 128 KiB
    const int K = 4096, ldc = 4096;
    const int t = threadIdx.x;
    const int lane = t & 63, wid = t >> 6;
    const int wr = wid >> 2, wc = wid & 3;              // 2 x 4 wave grid
    const int laneRow = lane & 15, laneK = (lane >> 4) << 3;
    const int rowA0 = blockIdx.y * 256, rowB0 = blockIdx.x * 256;

    f32x4 acc[8][4];
    #pragma unroll
    for (int i = 0; i < 8; i++)
        #pragma unroll
        for (int j = 0; j < 4; j++) acc[i][j] = (f32x4){0.f,0.f,0.f,0.f};

    // staging map: 4 x 16B loads per matrix per tile per thread; linear LDS dest,
    // inverse-swizzled GLOBAL source column-group (rule #21)
    int sidx[4], srow[4], scg[4];
    #pragma unroll
    for (int i = 0; i < 4; i++){
        int id = i * 512 + t;            // 0..2047
        sidx[i] = id;
        srow[i] = id >> 3;               // 0..255 (row in tile)
        int cg  = id & 7;                // 16B col-group
        scg[i]  = cg ^ (((id >> 5) & 1) << 1);   // flip 32B group when row&4
    }

    const int nT = K >> 6;   // 64 K-tiles
    // prologue: issue tile 0 into buf 0
    #pragma unroll
    for (int i = 0; i < 4; i++){
        gload16(A + (size_t)(rowA0 + srow[i]) * K + scg[i]*8, &lds[0*16384 + sidx[i]*8]);
        gload16(B + (size_t)(rowB0 + srow[i]) * K + scg[i]*8, &lds[1*16384 + sidx[i]*8]);
    }

    for (int kt = 0; kt < nT; ++kt){
        const int buf = kt & 1;
        __builtin_amdgcn_s_barrier();            // all prior reads of buf^1 complete
        if (kt + 1 < nT){
            const int kk = (kt + 1) << 6;
            const int bo = (buf ^ 1) * 32768;
            #pragma unroll
            for (int i = 0; i < 4; i++){
                gload16(A + (size_t)(rowA0 + srow[i]) * K + kk + scg[i]*8, &lds[bo + 0*16384 + sidx[i]*8]);
                gload16(B + (size_t)(rowB0 + srow[i]) * K + kk + scg[i]*8, &lds[bo + 1*16384 + sidx[i]*8]);
            }
            asm volatile("s_waitcnt vmcnt(8)" ::: "memory");   // tile kt landed; kt+1 in flight
        } else {
            asm volatile("s_waitcnt vmcnt(0)" ::: "memory");
        }
        __builtin_amdgcn_s_barrier();            // publish tile kt to all waves
        __builtin_amdgcn_sched_barrier(0);

        const char* lA = (const char*)&lds[(buf*2 + 0) * 16384];
        const char* lB = (const char*)&lds[(buf*2 + 1) * 16384];

        bf16x8 bfrag[2][4];
        #pragma unroll
        for (int kh = 0; kh < 2; kh++)
            #pragma unroll
            for (int ni = 0; ni < 4; ni++){
                int raw = (wc*64 + ni*16 + laneRow)*128 + (kh*32 + laneK)*2;
                bfrag[kh][ni] = *(const bf16x8*)(lB + swz(raw));
            }

        __builtin_amdgcn_s_setprio(1);
        #pragma unroll
        for (int mi = 0; mi < 8; mi++){
            int raw0 = (wr*128 + mi*16 + laneRow)*128 + laneK*2;
            int raw1 = raw0 + 64;
            bf16x8 a0 = *(const bf16x8*)(lA + swz(raw0));
            bf16x8 a1 = *(const bf16x8*)(lA + swz(raw1));
            #pragma unroll
            for (int ni = 0; ni < 4; ni++)
                acc[mi][ni] = __builtin_amdgcn_mfma_f32_16x16x32_bf16(a0, bfrag[0][ni], acc[mi][ni], 0, 0, 0);
            #pragma unroll
            for (int ni = 0; ni < 4; ni++)
                acc[mi][ni] = __builtin_amdgcn_mfma_f32_16x16x32_bf16(a1, bfrag[1][ni], acc[mi][ni], 0, 0, 0);
        }
        __builtin_amdgcn_s_setprio(0);
    }

    const int rowBase = rowA0 + wr*128;
    const int colBase = rowB0 + wc*64;
    #pragma unroll
    for (int mi = 0; mi < 8; mi++){
        #pragma unroll
        for (int ni = 0; ni < 4; ni++){
            f32x4 a = acc[mi][ni];
            const int cc = colBase + ni*16 + laneRow;
            const int rr = rowBase + mi*16 + ((lane >> 4) << 2);
            #pragma unroll
            for (int r = 0; r < 4; r++)
                C[(size_t)(rr + r) * ldc + cc] = f2bf(a[r]);
        }
    }
}

// ======================= verified 128^2 GEMM machinery ======================
template<int OF32>
__device__ __forceinline__ void gemm_body(
    const u16* __restrict__ A, const u16* __restrict__ B, void* __restrict__ Cv,
    int K, int ldc, int rowA0, int rowB0, float scale,
    u16* lA, u16* lB)
{
    const int t = threadIdx.x, lane = t & 63, w = t >> 6;
    const int wr = w >> 1, wc = w & 1;

    f32x4 acc[4][4];
    #pragma unroll
    for (int i = 0; i < 4; i++)
        #pragma unroll
        for (int j = 0; j < 4; j++) acc[i][j] = (f32x4){0.f,0.f,0.f,0.f};

    const int r0 = t >> 2,         c0 = (t & 3) << 3;
    const int r1 = (t + 256) >> 2, c1 = ((t + 256) & 3) << 3;
    const int laneRow = lane & 15, laneK = (lane >> 4) << 3;

    const int nK = K >> 5;
    for (int kt = 0; kt < nK; ++kt){
        const int kk = kt << 5;
        gload16(A + (size_t)(rowA0 + r0) * K + kk + c0, &lA[t * 8]);
        gload16(B + (size_t)(rowB0 + r0) * K + kk + c0, &lB[t * 8]);
        gload16(A + (size_t)(rowA0 + r1) * K + kk + c1, &lA[(t + 256) * 8]);
        gload16(B + (size_t)(rowB0 + r1) * K + kk + c1, &lB[(t + 256) * 8]);
        __syncthreads();

        bf16x8 af[4], bfv[4];
        #pragma unroll
        for (int mi = 0; mi < 4; mi++)
            af[mi] = *(const bf16x8*)&lA[(wr*64 + mi*16 + laneRow) * 32 + laneK];
        #pragma unroll
        for (int ni = 0; ni < 4; ni++)
            bfv[ni] = *(const bf16x8*)&lB[(wc*64 + ni*16 + laneRow) * 32 + laneK];

        #pragma unroll
        for (int mi = 0; mi < 4; mi++)
            #pragma unroll
            for (int ni = 0; ni < 4; ni++)
                acc[mi][ni] = __builtin_amdgcn_mfma_f32_16x16x32_bf16(af[mi], bfv[ni], acc[mi][ni], 0, 0, 0);
        __syncthreads();
    }

    const int rowBase = rowA0 + wr*64;
    const int colBase = rowB0 + wc*64;
    #pragma unroll
    for (int mi = 0; mi < 4; mi++){
        #pragma unroll
        for (int ni = 0; ni < 4; ni++){
            f32x4 a = acc[mi][ni];
            const int cc = colBase + ni*16 + laneRow;
            const int rr = rowBase + mi*16 + ((lane >> 4) << 2);
            #pragma unroll
            for (int r = 0; r < 4; r++){
                const size_t idx = (size_t)(rr + r) * ldc + cc;
                float v = a[r] * scale;
                if (OF32) ((float*)Cv)[idx] = v;
                else      ((u16*)Cv)[idx]  = f2bf(v);
            }
        }
    }
}

template<int OF32>
__global__ __launch_bounds__(256) void gemm_b16(
    const u16* __restrict__ A, const u16* __restrict__ B, void* __restrict__ Cv,
    int K, int ldc, long aBatch, long bBatch, long cBatch, float scale)
{
    __shared__ u16 lA[128*32];
    __shared__ u16 lB[128*32];
    const int b = blockIdx.z;
    const u16* Ab = A + (size_t)b * aBatch;
    const u16* Bb = B + (size_t)b * bBatch;
    void* Cb = OF32 ? (void*)((float*)Cv + (size_t)b * cBatch)
                    : (void*)((u16*)Cv  + (size_t)b * cBatch);
    gemm_body<OF32>(Ab, Bb, Cb, K, ldc, blockIdx.y * 128, blockIdx.x * 128, scale, lA, lB);
}

// gated redo of mk on the verified path (runs only if vfy flagged the 8-phase output)
__global__ __launch_bounds__(256) void proj_redo(
    const u32* __restrict__ flag,
    const u16* __restrict__ mem16, const u16* __restrict__ wk16, u16* __restrict__ mk16)
{
    if (*flag == 0) return;
    __shared__ u16 lA[128*32];
    __shared__ u16 lB[128*32];
    const int z = blockIdx.z;
    gemm_body<0>(mem16 + (size_t)z*2048*4096, wk16, mk16 + (size_t)z*2048*4096,
                 4096, 4096, blockIdx.y * 128, blockIdx.x * 128, 1.0f, lA, lB);
}

__global__ void flag_init(u32* f){ if (threadIdx.x == 0) *f = 0; }

// sample-verify mk16 vs direct dot: 16 samples per 256^2 tile (4096 checks)
__global__ __launch_bounds__(256) void vfy_mk(
    const u16* __restrict__ mem16, const u16* __restrict__ wk16,
    const u16* __restrict__ mk16, u32* __restrict__ flag)
{
    const int h = blockIdx.x * 256 + threadIdx.x;   // 0..4095
    const int tile = h >> 4, s = h & 15;
    const int row = (tile >> 4) * 256 + ((s * 67) & 255);
    const int col = (tile & 15) * 256 + ((s * 151 + 7) & 255);
    const u16* a = mem16 + (size_t)row * 4096;
    const u16* b = wk16 + (size_t)col * 4096;
    float s0 = 0.f;
    for (int k = 0; k < 4096; k++) s0 += bf2f(a[k]) * bf2f(b[k]);
    if (fabsf(s0 - bf2f(mk16[(size_t)row * 4096 + col])) > 0.05f) atomicOr(flag, 1u);
}

// ============================ aux kernels ==================================
__global__ __launch_bounds__(256) void cvt_f2b(
    const float* __restrict__ in, u16* __restrict__ out, long n8)
{
    for (long i = (long)blockIdx.x * 256 + threadIdx.x; i < n8; i += (long)gridDim.x * 256){
        f32x4 a = *(const f32x4*)(in + i*8);
        f32x4 b = *(const f32x4*)(in + i*8 + 4);
        u16x8 o;
        #pragma unroll
        for (int j = 0; j < 4; j++){ o[j] = ftrunc_bf(a[j]); o[j+4] = ftrunc_bf(b[j]); }
        *(u16x8*)(out + i*8) = o;
    }
}

__global__ __launch_bounds__(256) void transpose_u16(
    const u16* __restrict__ in, u16* __restrict__ out)
{
    __shared__ u16 tile[64][65];
    const size_t bi = (size_t)blockIdx.z * 2048 * 4096;
    const size_t bo = (size_t)blockIdx.z * 4096 * 2048;
    const int c0 = blockIdx.x * 64;
    const int r0 = blockIdx.y * 64;
    const int x = threadIdx.x & 63, y = threadIdx.x >> 6;
    #pragma unroll
    for (int i = 0; i < 16; i++){
        int r = y + i*4;
        tile[r][x] = in[bi + (size_t)(r0 + r) * 4096 + c0 + x];
    }
    __syncthreads();
    #pragma unroll
    for (int i = 0; i < 16; i++){
        int c = y + i*4;
        out[bo + (size_t)(c0 + c) * 2048 + r0 + x] = tile[x][c];
    }
}

__device__ __forceinline__ u32 shfl_u32(u32 v, int srcx){ return (u32)__shfl_xor((int)v, srcx, 64); }
__device__ __forceinline__ u64 shflxor64(u64 x, int off){
    u32 lo = (u32)x, hi = (u32)(x >> 32);
    lo = shfl_u32(lo, off); hi = shfl_u32(hi, off);
    return (((u64)hi) << 32) | lo;
}

__global__ __launch_bounds__(256) void softmax_argmax16(
    const u16* __restrict__ sc16, u16* __restrict__ probs,
    float* __restrict__ dout, const int* __restrict__ segp)
{
    const int row = blockIdx.x;
    const u16* s = sc16 + (size_t)row * 2048;
    u16* p = probs + (size_t)row * 2048;
    const int t = threadIdx.x, lane = t & 63, w = t >> 6;

    u16x8 rv = *(const u16x8*)(s + (size_t)t * 8);
    float v[8];
    #pragma unroll
    for (int j = 0; j < 8; j++) v[j] = bf2f(rv[j]);

    float mx = v[0];
    #pragma unroll
    for (int j = 1; j < 8; j++) mx = fmaxf(mx, v[j]);
    #pragma unroll
    for (int off = 32; off; off >>= 1) mx = fmaxf(mx, __shfl_xor(mx, off, 64));
    __shared__ float smax[4];
    if (lane == 0) smax[w] = mx;
    __syncthreads();
    mx = fmaxf(fmaxf(smax[0], smax[1]), fmaxf(smax[2], smax[3]));

    float e[8]; float sum = 0.f;
    #pragma unroll
    for (int j = 0; j < 8; j++){ e[j] = expf(v[j] - mx); sum += e[j]; }
    #pragma unroll
    for (int off = 32; off; off >>= 1) sum += __shfl_xor(sum, off, 64);
    __shared__ float ssum[4];
    if (lane == 0) ssum[w] = sum;
    __syncthreads();
    sum = ssum[0] + ssum[1] + ssum[2] + ssum[3];

    u16x8 pv;
    u64 best = 0ull;
    #pragma unroll
    for (int j = 0; j < 8; j++){
        u16 pb = f2bf(e[j] / sum);
        pv[j] = pb;
        u64 key = (((u64)pb) << 32) | (u32)(0x7FFFFFFF - (t*8 + j));
        if (key > best) best = key;
    }
    *(u16x8*)(p + (size_t)t * 8) = pv;

    #pragma unroll
    for (int off = 32; off; off >>= 1){
        u64 o = shflxor64(best, off);
        if (o > best) best = o;
    }
    __shared__ u64 sb[4];
    if (lane == 0) sb[w] = best;
    __syncthreads();
    if (t == 0){
        u64 bb = sb[0];
        if (sb[1] > bb) bb = sb[1];
        if (sb[2] > bb) bb = sb[2];
        if (sb[3] > bb) bb = sb[3];
        int idx = 0x7FFFFFFF - (int)(bb & 0xFFFFFFFFu);
        float hv = (float)(segp[0] - idx);
        dout[4194304 + row] = hv;
        if (row == 0) dout[4195328] = (hv < 4.0f) ? 1.0f : 0.0f;
    }
}

// ====================== FALLBACK KERNELS (R10 verbatim) =====================
template<int F32IN, int OF32>
__global__ __launch_bounds__(256) void gemm_bt(
    const void* __restrict__ Av, const void* __restrict__ Bv, void* __restrict__ Cv,
    int K, int ldc, float scale)
{
    __shared__ u16 lA[128*32];
    __shared__ u16 lB[128*32];
    const int rowA0 = blockIdx.y * 128;
    const int rowB0 = blockIdx.x * 128;
    const int t = threadIdx.x, lane = t & 63, w = t >> 6;
    const int wr = w >> 1, wc = w & 1;

    f32x4 acc[4][4];
    #pragma unroll
    for (int i = 0; i < 4; i++)
        #pragma unroll
        for (int j = 0; j < 4; j++) acc[i][j] = (f32x4){0.f,0.f,0.f,0.f};

    const int r0 = t >> 2,         c0 = (t & 3) << 3;
    const int r1 = (t + 256) >> 2, c1 = ((t + 256) & 3) << 3;
    const int laneRow = lane & 15, laneK = (lane >> 4) << 3;

    const int nK = K >> 5;
    for (int kt = 0; kt < nK; ++kt){
        const int kk = kt << 5;
        if (F32IN){
            const float* Af = (const float*)Av;
            const float* Bf = (const float*)Bv;
            f32x4 a00 = *(const f32x4*)&Af[(size_t)(rowA0 + r0) * K + kk + c0];
            f32x4 a01 = *(const f32x4*)&Af[(size_t)(rowA0 + r0) * K + kk + c0 + 4];
            f32x4 a10 = *(const f32x4*)&Af[(size_t)(rowA0 + r1) * K + kk + c1];
            f32x4 a11 = *(const f32x4*)&Af[(size_t)(rowA0 + r1) * K + kk + c1 + 4];
            f32x4 b00 = *(const f32x4*)&Bf[(size_t)(rowB0 + r0) * K + kk + c0];
            f32x4 b01 = *(const f32x4*)&Bf[(size_t)(rowB0 + r0) * K + kk + c0 + 4];
            f32x4 b10 = *(const f32x4*)&Bf[(size_t)(rowB0 + r1) * K + kk + c1];
            f32x4 b11 = *(const f32x4*)&Bf[(size_t)(rowB0 + r1) * K + kk + c1 + 4];
            u16x8 ua0, ua1, ub0, ub1;
            #pragma unroll
            for (int j = 0; j < 4; j++){
                ua0[j] = ftrunc_bf(a00[j]); ua0[j+4] = ftrunc_bf(a01[j]);
                ua1[j] = ftrunc_bf(a10[j]); ua1[j+4] = ftrunc_bf(a11[j]);
                ub0[j] = ftrunc_bf(b00[j]); ub0[j+4] = ftrunc_bf(b01[j]);
                ub1[j] = ftrunc_bf(b10[j]); ub1[j+4] = ftrunc_bf(b11[j]);
            }
            __syncthreads();
            *(u16x8*)&lA[(size_t)t * 8]         = ua0;
            *(u16x8*)&lA[(size_t)(t + 256) * 8] = ua1;
            *(u16x8*)&lB[(size_t)t * 8]         = ub0;
            *(u16x8*)&lB[(size_t)(t + 256) * 8] = ub1;
            __syncthreads();
        } else {
            const u16* Au = (const u16*)Av;
            const u16* Bu = (const u16*)Bv;
            gload16(Au + (size_t)(rowA0 + r0) * K + kk + c0, &lA[t * 8]);
            gload16(Bu + (size_t)(rowB0 + r0) * K + kk + c0, &lB[t * 8]);
            gload16(Au + (size_t)(rowA0 + r1) * K + kk + c1, &lA[(t + 256) * 8]);
            gload16(Bu + (size_t)(rowB0 + r1) * K + kk + c1, &lB[(t + 256) * 8]);
            __syncthreads();
        }

        bf16x8 af[4], bfv[4];
        #pragma unroll
        for (int mi = 0; mi < 4; mi++)
            af[mi] = *(const bf16x8*)&lA[(wr*64 + mi*16 + laneRow) * 32 + laneK];
        #pragma unroll
        for (int ni = 0; ni < 4; ni++)
            bfv[ni] = *(const bf16x8*)&lB[(wc*64 + ni*16 + laneRow) * 32 + laneK];

        #pragma unroll
        for (int mi = 0; mi < 4; mi++)
            #pragma unroll
            for (int ni = 0; ni < 4; ni++)
                acc[mi][ni] = __builtin_amdgcn_mfma_f32_16x16x32_bf16(af[mi], bfv[ni], acc[mi][ni], 0, 0, 0);
        if (!F32IN) __syncthreads();
    }

    const int rowBase = rowA0 + wr*64;
    const int colBase = rowB0 + wc*64;
    #pragma unroll
    for (int mi = 0; mi < 4; mi++){
        #pragma unroll
        for (int ni = 0; ni < 4; ni++){
            f32x4 a = acc[mi][ni];
            const int cc = colBase + ni*16 + laneRow;
            const int rr = rowBase + mi*16 + ((lane >> 4) << 2);
            #pragma unroll
            for (int r = 0; r < 4; r++){
                const size_t idx = (size_t)(rr + r) * ldc + cc;
                float v = a[r] * scale;
                if (OF32) ((float*)Cv)[idx] = v;
                else      ((u16*)Cv)[idx]  = f2bf(v);
            }
        }
    }
}

__global__ __launch_bounds__(256) void transpose_f2b(
    const float* __restrict__ in, u16* __restrict__ out)
{
    __shared__ u16 tile[64][65];
    const int c0 = blockIdx.x * 64;
    const int r0 = blockIdx.y * 64;
    const int x = threadIdx.x & 63, y = threadIdx.x >> 6;
    #pragma unroll
    for (int i = 0; i < 16; i++){
        int r = y + i*4;
        tile[r][x] = ftrunc_bf(in[(size_t)(r0 + r) * 4096 + c0 + x]);
    }
    __syncthreads();
    #pragma unroll
    for (int i = 0; i < 16; i++){
        int c = y + i*4;
        out[(size_t)(c0 + c) * 2048 + r0 + x] = tile[x][c];
    }
}

// ===========================================================================
extern "C" void kernel_launch(void* const* d_in, const int* in_sizes, int n_in,
                              void* d_out, int out_size, void* d_ws, size_t ws_size,
                              hipStream_t stream)
{
    const float* memory = (const float*)d_in[0];   // [2][2048][4096] f32 (bf16-valued)
    const float* inputs = (const float*)d_in[1];   // [2][512][4096]
    const float* wq     = (const float*)d_in[2];   // [4096][4096]
    const float* wk     = (const float*)d_in[3];   // [4096][4096]
    const int*   seg    = (const int*)d_in[4];
    float* out = (float*)d_out;

    char* ws = (char*)d_ws;
    dim3 blk(256);

    if (ws_size >= (152ull << 20)){
        // ---------------- FAST PATH ----------------
        u16* mem16 = (u16*)(ws);                        // 33.55 MB [2][2048][4096] = [4096][4096]
        u16* in16  = (u16*)(ws + 33554432);             //  8.39 MB [1024][4096]
        u16* wq16  = (u16*)(ws + 41943040);             // 33.55 MB
        u16* wk16  = (u16*)(ws + 75497472);             // 33.55 MB
        u16* xq16  = (u16*)(ws + 109051904);            //  8.39 MB
        u16* mk16  = (u16*)(ws + 117440512);            // 33.55 MB [4096][4096]; memT later
        u16* sc16  = (u16*)(ws + 150994944);            //  4.19 MB (also hosts flag pre-scores)
        u16* pr    = (u16*)(ws + 155189248);            //  4.19 MB
        u16* mt    = mk16;
        u32* flag  = (u32*)sc16;                        // free until scores GEMM

        cvt_f2b<<<dim3(2048), blk, 0, stream>>>(memory, mem16, 2097152L);
        cvt_f2b<<<dim3(1024), blk, 0, stream>>>(inputs, in16,   524288L);
        cvt_f2b<<<dim3(2048), blk, 0, stream>>>(wq,     wq16,  2097152L);
        cvt_f2b<<<dim3(2048), blk, 0, stream>>>(wk,     wk16,  2097152L);

        // combined mk (both batches = 4096 rows) on the 8-phase 256^2 kernel: 256 blocks = 1/CU
        gemm8ph<<<dim3(16, 16, 1), dim3(512), 131072, stream>>>(mem16, wk16, mk16);

        // safety net: sample-verify, redo on the verified path only if wrong
        flag_init<<<1, 64, 0, stream>>>(flag);
        vfy_mk<<<dim3(16), blk, 0, stream>>>(mem16, wk16, mk16, flag);
        proj_redo<<<dim3(32, 16, 2), blk, 0, stream>>>(flag, mem16, wk16, mk16);

        // xq on the verified 128^2 kernel (256 blocks)
        gemm_b16<0><<<dim3(32, 8, 1), blk, 0, stream>>>(in16, wq16, xq16, 4096, 4096,
                                                        0L, 0L, 0L, 1.0f);
        // scores (overwrites flag region — after redo)
        gemm_b16<0><<<dim3(16, 4, 2), blk, 0, stream>>>(xq16, mk16, sc16, 4096, 2048,
                                                        512L*4096, 2048L*4096, 512L*2048,
                                                        0.015625f);
        softmax_argmax16<<<dim3(1024), blk, 0, stream>>>(sc16, pr, out, seg);

        transpose_u16<<<dim3(64, 32, 2), blk, 0, stream>>>(mem16, mt);
        gemm_b16<1><<<dim3(32, 4, 2), blk, 0, stream>>>(pr, mt, out, 2048, 4096,
                                                        512L*2048, 4096L*2048, 512L*4096,
                                                        1.0f);
    } else {
        // ---------------- FALLBACK: R10 (passing) ----------------
        u16* xq16 = (u16*)(ws);
        u16* mk16 = (u16*)(ws + (8u<<20));
        u16* sc16 = (u16*)(ws + (24u<<20));
        u16* pr   = (u16*)(ws + (28u<<20));

        gemm_bt<1,0><<<dim3(32, 8, 1), blk, 0, stream>>>(inputs, wq, xq16, 4096, 4096, 1.0f);
        for (int b = 0; b < 2; ++b){
            const float* memb = memory + (size_t)b * 2048 * 4096;
            gemm_bt<1,0><<<dim3(32, 16, 1), blk, 0, stream>>>(memb, wk, mk16, 4096, 4096, 1.0f);
            gemm_bt<0,0><<<dim3(16, 4, 1), blk, 0, stream>>>(xq16 + (size_t)b*512*4096, mk16,
                                                             sc16 + (size_t)b*512*2048,
                                                             4096, 2048, 0.015625f);
        }
        softmax_argmax16<<<dim3(1024), blk, 0, stream>>>(sc16, pr, out, seg);
        for (int b = 0; b < 2; ++b){
            const float* memb = memory + (size_t)b * 2048 * 4096;
            transpose_f2b<<<dim3(64, 32, 1), blk, 0, stream>>>(memb, mk16);
            gemm_bt<0,1><<<dim3(32, 4, 1), blk, 0, stream>>>(pr + (size_t)b*512*2048, mk16,
                                                             out + (size_t)b*512*4096,
                                                             2048, 4096, 1.0f);
        }
    }
}

// Round 13
// 559.072 us; speedup vs baseline: 1.0086x; 1.0086x over previous
//
#include <hip/hip_runtime.h>

typedef unsigned short u16;
typedef unsigned int   u32;
typedef unsigned long long u64;
typedef __attribute__((ext_vector_type(8))) short bf16x8;
typedef __attribute__((ext_vector_type(8))) unsigned short u16x8;
typedef __attribute__((ext_vector_type(4))) float f32x4;

__device__ __forceinline__ float bf2f(u16 h){ u32 u = ((u32)h)<<16; return __builtin_bit_cast(float, u); }
__device__ __forceinline__ u16 f2bf(float f){
    u32 u = __builtin_bit_cast(u32, f);
    return (u16)((u + 0x7FFFu + ((u>>16)&1u)) >> 16);   // RNE
}
__device__ __forceinline__ u16 ftrunc_bf(float f){      // exact for bf16-valued f32
    return (u16)(__builtin_bit_cast(u32, f) >> 16);
}

__device__ __forceinline__ void gload16(const void* g, void* l){
    __builtin_amdgcn_global_load_lds((const __attribute__((address_space(1))) void*)g,
                                     (__attribute__((address_space(3))) void*)l, 16, 0, 0);
}

// ===================== 8-phase-style 256x256 GEMM (mk) =====================
// C[4096][4096] = A[4096][4096]@B[4096][4096]^T bf16. 512thr=8 waves(2x4), BK=64,
// dbuf 128KiB LDS, counted vmcnt(8), raw s_barrier, 3-bit row swizzle, setprio.
__global__ __launch_bounds__(512, 2) void gemm8ph(
    const u16* __restrict__ A, const u16* __restrict__ B, u16* __restrict__ C)
{
    extern __shared__ u16 lds[];   // [2 buf][2 mat][16384] u16 = 128 KiB
    const int K = 4096, ldc = 4096;
    const int t = threadIdx.x;
    const int lane = t & 63, wid = t >> 6;
    const int wr = wid >> 2, wc = wid & 3;
    const int laneRow = lane & 15, laneK = (lane >> 4) << 3;

    // bijective XCD chunk remap (256 blocks, 8 XCDs, 32/chunk)
    int bid = blockIdx.y * 16 + blockIdx.x;
    bid = (bid & 7) * 32 + (bid >> 3);
    const int rowA0 = (bid >> 4) * 256, rowB0 = (bid & 15) * 256;

    f32x4 acc[8][4];
    #pragma unroll
    for (int i = 0; i < 8; i++)
        #pragma unroll
        for (int j = 0; j < 4; j++) acc[i][j] = (f32x4){0.f,0.f,0.f,0.f};

    // staging: 4 x 16B loads/matrix/tile/thread; linear LDS dest,
    // inverse-swizzled global source chunk: scg = cg ^ (row&7)   [rule #21]
    int sidx[4], srow[4], scg[4];
    #pragma unroll
    for (int i = 0; i < 4; i++){
        int id = i * 512 + t;                 // 0..2047
        sidx[i] = id;
        srow[i] = id >> 3;                    // row 0..255
        scg[i]  = (id & 7) ^ ((id >> 3) & 7); // 16B col-group, 3-bit row XOR
    }

    const int nT = K >> 6;
    #pragma unroll
    for (int i = 0; i < 4; i++){
        gload16(A + (size_t)(rowA0 + srow[i]) * K + scg[i]*8, &lds[0*16384 + sidx[i]*8]);
        gload16(B + (size_t)(rowB0 + srow[i]) * K + scg[i]*8, &lds[1*16384 + sidx[i]*8]);
    }

    for (int kt = 0; kt < nT; ++kt){
        const int buf = kt & 1;
        __builtin_amdgcn_s_barrier();
        if (kt + 1 < nT){
            const int kk = (kt + 1) << 6;
            const int bo = (buf ^ 1) * 32768;
            #pragma unroll
            for (int i = 0; i < 4; i++){
                gload16(A + (size_t)(rowA0 + srow[i]) * K + kk + scg[i]*8, &lds[bo + 0*16384 + sidx[i]*8]);
                gload16(B + (size_t)(rowB0 + srow[i]) * K + kk + scg[i]*8, &lds[bo + 1*16384 + sidx[i]*8]);
            }
            asm volatile("s_waitcnt vmcnt(8)" ::: "memory");
        } else {
            asm volatile("s_waitcnt vmcnt(0)" ::: "memory");
        }
        __builtin_amdgcn_s_barrier();
        __builtin_amdgcn_sched_barrier(0);

        const char* lA = (const char*)&lds[(buf*2 + 0) * 16384];
        const char* lB = (const char*)&lds[(buf*2 + 1) * 16384];

        bf16x8 bfrag[2][4];
        #pragma unroll
        for (int kh = 0; kh < 2; kh++)
            #pragma unroll
            for (int ni = 0; ni < 4; ni++){
                int row = wc*64 + ni*16 + laneRow;
                int raw = row*128 + kh*64 + (laneK<<1);
                bfrag[kh][ni] = *(const bf16x8*)(lB + (raw ^ ((row & 7) << 4)));
            }

        __builtin_amdgcn_s_setprio(1);
        #pragma unroll
        for (int mi = 0; mi < 8; mi++){
            int row = wr*128 + mi*16 + laneRow;
            int mask = (row & 7) << 4;
            int raw0 = row*128 + (laneK<<1);
            bf16x8 a0 = *(const bf16x8*)(lA + (raw0 ^ mask));
            bf16x8 a1 = *(const bf16x8*)(lA + ((raw0 + 64) ^ mask));
            #pragma unroll
            for (int ni = 0; ni < 4; ni++)
                acc[mi][ni] = __builtin_amdgcn_mfma_f32_16x16x32_bf16(a0, bfrag[0][ni], acc[mi][ni], 0, 0, 0);
            #pragma unroll
            for (int ni = 0; ni < 4; ni++)
                acc[mi][ni] = __builtin_amdgcn_mfma_f32_16x16x32_bf16(a1, bfrag[1][ni], acc[mi][ni], 0, 0, 0);
        }
        __builtin_amdgcn_s_setprio(0);
    }

    const int rowBase = rowA0 + wr*128;
    const int colBase = rowB0 + wc*64;
    #pragma unroll
    for (int mi = 0; mi < 8; mi++){
        #pragma unroll
        for (int ni = 0; ni < 4; ni++){
            f32x4 a = acc[mi][ni];
            const int cc = colBase + ni*16 + laneRow;
            const int rr = rowBase + mi*16 + ((lane >> 4) << 2);
            #pragma unroll
            for (int r = 0; r < 4; r++)
                C[(size_t)(rr + r) * ldc + cc] = f2bf(a[r]);
        }
    }
}

// ======================= verified 128^2 GEMM machinery ======================
template<int OF32>
__device__ __forceinline__ void gemm_body(
    const u16* __restrict__ A, const u16* __restrict__ B, void* __restrict__ Cv,
    int K, int ldc, int rowA0, int rowB0, float scale,
    u16* lA, u16* lB)
{
    const int t = threadIdx.x, lane = t & 63, w = t >> 6;
    const int wr = w >> 1, wc = w & 1;

    f32x4 acc[4][4];
    #pragma unroll
    for (int i = 0; i < 4; i++)
        #pragma unroll
        for (int j = 0; j < 4; j++) acc[i][j] = (f32x4){0.f,0.f,0.f,0.f};

    const int r0 = t >> 2,         c0 = (t & 3) << 3;
    const int r1 = (t + 256) >> 2, c1 = ((t + 256) & 3) << 3;
    const int laneRow = lane & 15, laneK = (lane >> 4) << 3;

    const int nK = K >> 5;
    for (int kt = 0; kt < nK; ++kt){
        const int kk = kt << 5;
        gload16(A + (size_t)(rowA0 + r0) * K + kk + c0, &lA[t * 8]);
        gload16(B + (size_t)(rowB0 + r0) * K + kk + c0, &lB[t * 8]);
        gload16(A + (size_t)(rowA0 + r1) * K + kk + c1, &lA[(t + 256) * 8]);
        gload16(B + (size_t)(rowB0 + r1) * K + kk + c1, &lB[(t + 256) * 8]);
        __syncthreads();

        bf16x8 af[4], bfv[4];
        #pragma unroll
        for (int mi = 0; mi < 4; mi++)
            af[mi] = *(const bf16x8*)&lA[(wr*64 + mi*16 + laneRow) * 32 + laneK];
        #pragma unroll
        for (int ni = 0; ni < 4; ni++)
            bfv[ni] = *(const bf16x8*)&lB[(wc*64 + ni*16 + laneRow) * 32 + laneK];

        #pragma unroll
        for (int mi = 0; mi < 4; mi++)
            #pragma unroll
            for (int ni = 0; ni < 4; ni++)
                acc[mi][ni] = __builtin_amdgcn_mfma_f32_16x16x32_bf16(af[mi], bfv[ni], acc[mi][ni], 0, 0, 0);
        __syncthreads();
    }

    const int rowBase = rowA0 + wr*64;
    const int colBase = rowB0 + wc*64;
    #pragma unroll
    for (int mi = 0; mi < 4; mi++){
        #pragma unroll
        for (int ni = 0; ni < 4; ni++){
            f32x4 a = acc[mi][ni];
            const int cc = colBase + ni*16 + laneRow;
            const int rr = rowBase + mi*16 + ((lane >> 4) << 2);
            #pragma unroll
            for (int r = 0; r < 4; r++){
                const size_t idx = (size_t)(rr + r) * ldc + cc;
                float v = a[r] * scale;
                if (OF32) ((float*)Cv)[idx] = v;
                else      ((u16*)Cv)[idx]  = f2bf(v);
            }
        }
    }
}

template<int OF32>
__global__ __launch_bounds__(256) void gemm_b16(
    const u16* __restrict__ A, const u16* __restrict__ B, void* __restrict__ Cv,
    int K, int ldc, long aBatch, long bBatch, long cBatch, float scale)
{
    __shared__ u16 lA[128*32];
    __shared__ u16 lB[128*32];
    const int b = blockIdx.z;
    const u16* Ab = A + (size_t)b * aBatch;
    const u16* Bb = B + (size_t)b * bBatch;
    void* Cb = OF32 ? (void*)((float*)Cv + (size_t)b * cBatch)
                    : (void*)((u16*)Cv  + (size_t)b * cBatch);
    gemm_body<OF32>(Ab, Bb, Cb, K, ldc, blockIdx.y * 128, blockIdx.x * 128, scale, lA, lB);
}

// gated redo of mk (runs only if vfy flagged)
__global__ __launch_bounds__(256) void proj_redo(
    const u32* __restrict__ flag,
    const u16* __restrict__ mem16, const u16* __restrict__ wk16, u16* __restrict__ mk16)
{
    if (*flag == 0) return;
    __shared__ u16 lA[128*32];
    __shared__ u16 lB[128*32];
    gemm_body<0>(mem16, wk16, mk16, 4096, 4096, blockIdx.y * 128, blockIdx.x * 128, 1.0f, lA, lB);
}

__global__ void flag_init(u32* f){ if (threadIdx.x == 0) *f = 0; }

// cheap sample-verify: 512 vectorized dots (2 samples per 256^2 tile)
__global__ __launch_bounds__(256) void vfy_mk(
    const u16* __restrict__ mem16, const u16* __restrict__ wk16,
    const u16* __restrict__ mk16, u32* __restrict__ flag)
{
    const int tid = blockIdx.x * 256 + threadIdx.x;   // 0..511
    const int tile = tid & 255;
    const int row = (tile >> 4) * 256 + ((tid * 67 + 13) & 255);
    const int col = (tile & 15) * 256 + ((tid * 151 + 7) & 255);
    const u16* a = mem16 + (size_t)row * 4096;
    const u16* b = wk16 + (size_t)col * 4096;
    float s = 0.f;
    for (int k8 = 0; k8 < 512; k8++){
        u16x8 av = *(const u16x8*)(a + k8*8);
        u16x8 bv = *(const u16x8*)(b + k8*8);
        #pragma unroll
        for (int j = 0; j < 8; j++) s += bf2f(av[j]) * bf2f(bv[j]);
    }
    if (fabsf(s - bf2f(mk16[(size_t)row * 4096 + col])) > 0.05f) atomicOr(flag, 1u);
}

// ============================ aux kernels ==================================
// single fused f32->bf16 conversion over all four inputs
__global__ __launch_bounds__(256) void cvt_all(
    const float* __restrict__ m, const float* __restrict__ in,
    const float* __restrict__ q, const float* __restrict__ k,
    u16* __restrict__ m16, u16* __restrict__ in16,
    u16* __restrict__ q16, u16* __restrict__ k16)
{
    const long N0 = 2097152, N1 = N0 + 524288, N2 = N1 + 2097152, N3 = N2 + 2097152;
    for (long g = (long)blockIdx.x * 256 + threadIdx.x; g < N3; g += (long)gridDim.x * 256){
        const float* src; u16* dst; long o;
        if      (g < N0){ src = m;  dst = m16;  o = g; }
        else if (g < N1){ src = in; dst = in16; o = g - N0; }
        else if (g < N2){ src = q;  dst = q16;  o = g - N1; }
        else            { src = k;  dst = k16;  o = g - N2; }
        f32x4 a = *(const f32x4*)(src + o*8);
        f32x4 b = *(const f32x4*)(src + o*8 + 4);
        u16x8 v;
        #pragma unroll
        for (int j = 0; j < 4; j++){ v[j] = ftrunc_bf(a[j]); v[j+4] = ftrunc_bf(b[j]); }
        *(u16x8*)(dst + o*8) = v;
    }
}

__global__ __launch_bounds__(256) void transpose_u16(
    const u16* __restrict__ in, u16* __restrict__ out)
{
    __shared__ u16 tile[64][65];
    const size_t bi = (size_t)blockIdx.z * 2048 * 4096;
    const size_t bo = (size_t)blockIdx.z * 4096 * 2048;
    const int c0 = blockIdx.x * 64;
    const int r0 = blockIdx.y * 64;
    const int x = threadIdx.x & 63, y = threadIdx.x >> 6;
    #pragma unroll
    for (int i = 0; i < 16; i++){
        int r = y + i*4;
        tile[r][x] = in[bi + (size_t)(r0 + r) * 4096 + c0 + x];
    }
    __syncthreads();
    #pragma unroll
    for (int i = 0; i < 16; i++){
        int c = y + i*4;
        out[bo + (size_t)(c0 + c) * 2048 + r0 + x] = tile[x][c];
    }
}

__device__ __forceinline__ u32 shfl_u32(u32 v, int srcx){ return (u32)__shfl_xor((int)v, srcx, 64); }
__device__ __forceinline__ u64 shflxor64(u64 x, int off){
    u32 lo = (u32)x, hi = (u32)(x >> 32);
    lo = shfl_u32(lo, off); hi = shfl_u32(hi, off);
    return (((u64)hi) << 32) | lo;
}

__global__ __launch_bounds__(256) void softmax_argmax16(
    const u16* __restrict__ sc16, u16* __restrict__ probs,
    float* __restrict__ dout, const int* __restrict__ segp)
{
    const int row = blockIdx.x;
    const u16* s = sc16 + (size_t)row * 2048;
    u16* p = probs + (size_t)row * 2048;
    const int t = threadIdx.x, lane = t & 63, w = t >> 6;

    u16x8 rv = *(const u16x8*)(s + (size_t)t * 8);
    float v[8];
    #pragma unroll
    for (int j = 0; j < 8; j++) v[j] = bf2f(rv[j]);

    float mx = v[0];
    #pragma unroll
    for (int j = 1; j < 8; j++) mx = fmaxf(mx, v[j]);
    #pragma unroll
    for (int off = 32; off; off >>= 1) mx = fmaxf(mx, __shfl_xor(mx, off, 64));
    __shared__ float smax[4];
    if (lane == 0) smax[w] = mx;
    __syncthreads();
    mx = fmaxf(fmaxf(smax[0], smax[1]), fmaxf(smax[2], smax[3]));

    float e[8]; float sum = 0.f;
    #pragma unroll
    for (int j = 0; j < 8; j++){ e[j] = expf(v[j] - mx); sum += e[j]; }
    #pragma unroll
    for (int off = 32; off; off >>= 1) sum += __shfl_xor(sum, off, 64);
    __shared__ float ssum[4];
    if (lane == 0) ssum[w] = sum;
    __syncthreads();
    sum = ssum[0] + ssum[1] + ssum[2] + ssum[3];

    u16x8 pv;
    u64 best = 0ull;
    #pragma unroll
    for (int j = 0; j < 8; j++){
        u16 pb = f2bf(e[j] / sum);
        pv[j] = pb;
        u64 key = (((u64)pb) << 32) | (u32)(0x7FFFFFFF - (t*8 + j));
        if (key > best) best = key;
    }
    *(u16x8*)(p + (size_t)t * 8) = pv;

    #pragma unroll
    for (int off = 32; off; off >>= 1){
        u64 o = shflxor64(best, off);
        if (o > best) best = o;
    }
    __shared__ u64 sb[4];
    if (lane == 0) sb[w] = best;
    __syncthreads();
    if (t == 0){
        u64 bb = sb[0];
        if (sb[1] > bb) bb = sb[1];
        if (sb[2] > bb) bb = sb[2];
        if (sb[3] > bb) bb = sb[3];
        int idx = 0x7FFFFFFF - (int)(bb & 0xFFFFFFFFu);
        float hv = (float)(segp[0] - idx);
        dout[4194304 + row] = hv;
        if (row == 0) dout[4195328] = (hv < 4.0f) ? 1.0f : 0.0f;
    }
}

// ====================== FALLBACK KERNELS (R10 verbatim) =====================
template<int F32IN, int OF32>
__global__ __launch_bounds__(256) void gemm_bt(
    const void* __restrict__ Av, const void* __restrict__ Bv, void* __restrict__ Cv,
    int K, int ldc, float scale)
{
    __shared__ u16 lA[128*32];
    __shared__ u16 lB[128*32];
    const int rowA0 = blockIdx.y * 128;
    const int rowB0 = blockIdx.x * 128;
    const int t = threadIdx.x, lane = t & 63, w = t >> 6;
    const int wr = w >> 1, wc = w & 1;

    f32x4 acc[4][4];
    #pragma unroll
    for (int i = 0; i < 4; i++)
        #pragma unroll
        for (int j = 0; j < 4; j++) acc[i][j] = (f32x4){0.f,0.f,0.f,0.f};

    const int r0 = t >> 2,         c0 = (t & 3) << 3;
    const int r1 = (t + 256) >> 2, c1 = ((t + 256) & 3) << 3;
    const int laneRow = lane & 15, laneK = (lane >> 4) << 3;

    const int nK = K >> 5;
    for (int kt = 0; kt < nK; ++kt){
        const int kk = kt << 5;
        if (F32IN){
            const float* Af = (const float*)Av;
            const float* Bf = (const float*)Bv;
            f32x4 a00 = *(const f32x4*)&Af[(size_t)(rowA0 + r0) * K + kk + c0];
            f32x4 a01 = *(const f32x4*)&Af[(size_t)(rowA0 + r0) * K + kk + c0 + 4];
            f32x4 a10 = *(const f32x4*)&Af[(size_t)(rowA0 + r1) * K + kk + c1];
            f32x4 a11 = *(const f32x4*)&Af[(size_t)(rowA0 + r1) * K + kk + c1 + 4];
            f32x4 b00 = *(const f32x4*)&Bf[(size_t)(rowB0 + r0) * K + kk + c0];
            f32x4 b01 = *(const f32x4*)&Bf[(size_t)(rowB0 + r0) * K + kk + c0 + 4];
            f32x4 b10 = *(const f32x4*)&Bf[(size_t)(rowB0 + r1) * K + kk + c1];
            f32x4 b11 = *(const f32x4*)&Bf[(size_t)(rowB0 + r1) * K + kk + c1 + 4];
            u16x8 ua0, ua1, ub0, ub1;
            #pragma unroll
            for (int j = 0; j < 4; j++){
                ua0[j] = ftrunc_bf(a00[j]); ua0[j+4] = ftrunc_bf(a01[j]);
                ua1[j] = ftrunc_bf(a10[j]); ua1[j+4] = ftrunc_bf(a11[j]);
                ub0[j] = ftrunc_bf(b00[j]); ub0[j+4] = ftrunc_bf(b01[j]);
                ub1[j] = ftrunc_bf(b10[j]); ub1[j+4] = ftrunc_bf(b11[j]);
            }
            __syncthreads();
            *(u16x8*)&lA[(size_t)t * 8]         = ua0;
            *(u16x8*)&lA[(size_t)(t + 256) * 8] = ua1;
            *(u16x8*)&lB[(size_t)t * 8]         = ub0;
            *(u16x8*)&lB[(size_t)(t + 256) * 8] = ub1;
            __syncthreads();
        } else {
            const u16* Au = (const u16*)Av;
            const u16* Bu = (const u16*)Bv;
            gload16(Au + (size_t)(rowA0 + r0) * K + kk + c0, &lA[t * 8]);
            gload16(Bu + (size_t)(rowB0 + r0) * K + kk + c0, &lB[t * 8]);
            gload16(Au + (size_t)(rowA0 + r1) * K + kk + c1, &lA[(t + 256) * 8]);
            gload16(Bu + (size_t)(rowB0 + r1) * K + kk + c1, &lB[(t + 256) * 8]);
            __syncthreads();
        }

        bf16x8 af[4], bfv[4];
        #pragma unroll
        for (int mi = 0; mi < 4; mi++)
            af[mi] = *(const bf16x8*)&lA[(wr*64 + mi*16 + laneRow) * 32 + laneK];
        #pragma unroll
        for (int ni = 0; ni < 4; ni++)
            bfv[ni] = *(const bf16x8*)&lB[(wc*64 + ni*16 + laneRow) * 32 + laneK];

        #pragma unroll
        for (int mi = 0; mi < 4; mi++)
            #pragma unroll
            for (int ni = 0; ni < 4; ni++)
                acc[mi][ni] = __builtin_amdgcn_mfma_f32_16x16x32_bf16(af[mi], bfv[ni], acc[mi][ni], 0, 0, 0);
        if (!F32IN) __syncthreads();
    }

    const int rowBase = rowA0 + wr*64;
    const int colBase = rowB0 + wc*64;
    #pragma unroll
    for (int mi = 0; mi < 4; mi++){
        #pragma unroll
        for (int ni = 0; ni < 4; ni++){
            f32x4 a = acc[mi][ni];
            const int cc = colBase + ni*16 + laneRow;
            const int rr = rowBase + mi*16 + ((lane >> 4) << 2);
            #pragma unroll
            for (int r = 0; r < 4; r++){
                const size_t idx = (size_t)(rr + r) * ldc + cc;
                float v = a[r] * scale;
                if (OF32) ((float*)Cv)[idx] = v;
                else      ((u16*)Cv)[idx]  = f2bf(v);
            }
        }
    }
}

__global__ __launch_bounds__(256) void transpose_f2b(
    const float* __restrict__ in, u16* __restrict__ out)
{
    __shared__ u16 tile[64][65];
    const int c0 = blockIdx.x * 64;
    const int r0 = blockIdx.y * 64;
    const int x = threadIdx.x & 63, y = threadIdx.x >> 6;
    #pragma unroll
    for (int i = 0; i < 16; i++){
        int r = y + i*4;
        tile[r][x] = ftrunc_bf(in[(size_t)(r0 + r) * 4096 + c0 + x]);
    }
    __syncthreads();
    #pragma unroll
    for (int i = 0; i < 16; i++){
        int c = y + i*4;
        out[(size_t)(c0 + c) * 2048 + r0 + x] = tile[x][c];
    }
}

// ===========================================================================
extern "C" void kernel_launch(void* const* d_in, const int* in_sizes, int n_in,
                              void* d_out, int out_size, void* d_ws, size_t ws_size,
                              hipStream_t stream)
{
    const float* memory = (const float*)d_in[0];   // [2][2048][4096] f32 (bf16-valued)
    const float* inputs = (const float*)d_in[1];   // [2][512][4096]
    const float* wq     = (const float*)d_in[2];   // [4096][4096]
    const float* wk     = (const float*)d_in[3];   // [4096][4096]
    const int*   seg    = (const int*)d_in[4];
    float* out = (float*)d_out;

    char* ws = (char*)d_ws;
    dim3 blk(256);

    if (ws_size >= (152ull << 20)){
        // ---------------- FAST PATH ----------------
        u16* mem16 = (u16*)(ws);                        // [4096][4096] (both batches)
        u16* in16  = (u16*)(ws + 33554432);             // [1024][4096]
        u16* wq16  = (u16*)(ws + 41943040);
        u16* wk16  = (u16*)(ws + 75497472);
        u16* xq16  = (u16*)(ws + 109051904);
        u16* mk16  = (u16*)(ws + 117440512);            // [4096][4096]; memT later
        u16* sc16  = (u16*)(ws + 150994944);
        u16* pr    = (u16*)(ws + 155189248);
        u16* mt    = mk16;
        u32* flag  = (u32*)sc16;                        // free until scores GEMM

        cvt_all<<<dim3(4096), blk, 0, stream>>>(memory, inputs, wq, wk,
                                                mem16, in16, wq16, wk16);

        // combined mk on the 8-phase 256^2 kernel: 256 blocks = 1/CU
        gemm8ph<<<dim3(16, 16, 1), dim3(512), 131072, stream>>>(mem16, wk16, mk16);

        flag_init<<<1, 64, 0, stream>>>(flag);
        vfy_mk<<<dim3(2), blk, 0, stream>>>(mem16, wk16, mk16, flag);
        proj_redo<<<dim3(32, 32, 1), blk, 0, stream>>>(flag, mem16, wk16, mk16);

        // xq on verified 128^2 (256 blocks)
        gemm_b16<0><<<dim3(32, 8, 1), blk, 0, stream>>>(in16, wq16, xq16, 4096, 4096,
                                                        0L, 0L, 0L, 1.0f);
        // scores (overwrites flag region — after redo)
        gemm_b16<0><<<dim3(16, 4, 2), blk, 0, stream>>>(xq16, mk16, sc16, 4096, 2048,
                                                        512L*4096, 2048L*4096, 512L*2048,
                                                        0.015625f);
        softmax_argmax16<<<dim3(1024), blk, 0, stream>>>(sc16, pr, out, seg);

        transpose_u16<<<dim3(64, 32, 2), blk, 0, stream>>>(mem16, mt);
        gemm_b16<1><<<dim3(32, 4, 2), blk, 0, stream>>>(pr, mt, out, 2048, 4096,
                                                        512L*2048, 4096L*2048, 512L*4096,
                                                        1.0f);
    } else {
        // ---------------- FALLBACK: R10 (passing) ----------------
        u16* xq16 = (u16*)(ws);
        u16* mk16 = (u16*)(ws + (8u<<20));
        u16* sc16 = (u16*)(ws + (24u<<20));
        u16* pr   = (u16*)(ws + (28u<<20));

        gemm_bt<1,0><<<dim3(32, 8, 1), blk, 0, stream>>>(inputs, wq, xq16, 4096, 4096, 1.0f);
        for (int b = 0; b < 2; ++b){
            const float* memb = memory + (size_t)b * 2048 * 4096;
            gemm_bt<1,0><<<dim3(32, 16, 1), blk, 0, stream>>>(memb, wk, mk16, 4096, 4096, 1.0f);
            gemm_bt<0,0><<<dim3(16, 4, 1), blk, 0, stream>>>(xq16 + (size_t)b*512*4096, mk16,
                                                             sc16 + (size_t)b*512*2048,
                                                             4096, 2048, 0.015625f);
        }
        softmax_argmax16<<<dim3(1024), blk, 0, stream>>>(sc16, pr, out, seg);
        for (int b = 0; b < 2; ++b){
            const float* memb = memory + (size_t)b * 2048 * 4096;
            transpose_f2b<<<dim3(64, 32, 1), blk, 0, stream>>>(memb, mk16);
            gemm_bt<0,1><<<dim3(32, 4, 1), blk, 0, stream>>>(pr + (size_t)b*512*2048, mk16,
                                                             out + (size_t)b*512*4096,
                                                             2048, 4096, 1.0f);
        }
    }
}

// Round 14
// 422.371 us; speedup vs baseline: 1.3350x; 1.3237x over previous
//
#include <hip/hip_runtime.h>

typedef unsigned short u16;
typedef unsigned int   u32;
typedef unsigned long long u64;
typedef __attribute__((ext_vector_type(8))) short bf16x8;
typedef __attribute__((ext_vector_type(8))) unsigned short u16x8;
typedef __attribute__((ext_vector_type(4))) float f32x4;

__device__ __forceinline__ float bf2f(u16 h){ u32 u = ((u32)h)<<16; return __builtin_bit_cast(float, u); }
__device__ __forceinline__ u16 f2bf(float f){
    u32 u = __builtin_bit_cast(u32, f);
    return (u16)((u + 0x7FFFu + ((u>>16)&1u)) >> 16);   // RNE
}
__device__ __forceinline__ u16 ftrunc_bf(float f){      // exact for bf16-valued f32
    return (u16)(__builtin_bit_cast(u32, f) >> 16);
}

__device__ __forceinline__ void gload16(const void* g, void* l){
    __builtin_amdgcn_global_load_lds((const __attribute__((address_space(1))) void*)g,
                                     (__attribute__((address_space(3))) void*)l, 16, 0, 0);
}

// ============== 8-phase-style 256x256 GEMM: mk (256 blk) + xq (64 blk) ==============
// blocks 0..255:  mk[4096][4096] = mem16 @ wk16^T
// blocks 256..319: xq[1024][4096] = in16 @ wq16^T
// 512thr=8 waves(2x4), BK=64, dbuf 128KiB LDS, counted vmcnt(8), raw s_barrier,
// 3-bit row swizzle both-sides, setprio.
__global__ __launch_bounds__(512, 2) void gemm8ph(
    const u16* __restrict__ mem16, const u16* __restrict__ wk16, u16* __restrict__ mk16,
    const u16* __restrict__ in16,  const u16* __restrict__ wq16, u16* __restrict__ xq16)
{
    extern __shared__ u16 lds[];   // [2 buf][2 mat][16384] u16 = 128 KiB
    const int K = 4096, ldc = 4096;
    const int t = threadIdx.x;
    const int lane = t & 63, wid = t >> 6;
    const int wr = wid >> 2, wc = wid & 3;
    const int laneRow = lane & 15, laneK = (lane >> 4) << 3;

    // bijective XCD chunk remap over 320 blocks (8 XCDs x 40)
    int bid = blockIdx.x;
    bid = (bid & 7) * 40 + (bid >> 3);

    const u16 *A, *B; u16* C;
    int rowA0, rowB0;
    if (bid < 256){
        A = mem16; B = wk16; C = mk16;
        rowA0 = (bid >> 4) * 256; rowB0 = (bid & 15) * 256;
    } else {
        const int xb = bid - 256;
        A = in16; B = wq16; C = xq16;
        rowA0 = (xb >> 4) * 256; rowB0 = (xb & 15) * 256;
    }

    f32x4 acc[8][4];
    #pragma unroll
    for (int i = 0; i < 8; i++)
        #pragma unroll
        for (int j = 0; j < 4; j++) acc[i][j] = (f32x4){0.f,0.f,0.f,0.f};

    // staging: linear LDS dest, inverse-swizzled global source (rule #21)
    int sidx[4], srow[4], scg[4];
    #pragma unroll
    for (int i = 0; i < 4; i++){
        int id = i * 512 + t;                 // 0..2047
        sidx[i] = id;
        srow[i] = id >> 3;                    // row 0..255
        scg[i]  = (id & 7) ^ ((id >> 3) & 7); // 16B col-group, 3-bit row XOR
    }

    const int nT = K >> 6;
    #pragma unroll
    for (int i = 0; i < 4; i++){
        gload16(A + (size_t)(rowA0 + srow[i]) * K + scg[i]*8, &lds[0*16384 + sidx[i]*8]);
        gload16(B + (size_t)(rowB0 + srow[i]) * K + scg[i]*8, &lds[1*16384 + sidx[i]*8]);
    }

    for (int kt = 0; kt < nT; ++kt){
        const int buf = kt & 1;
        __builtin_amdgcn_s_barrier();
        if (kt + 1 < nT){
            const int kk = (kt + 1) << 6;
            const int bo = (buf ^ 1) * 32768;
            #pragma unroll
            for (int i = 0; i < 4; i++){
                gload16(A + (size_t)(rowA0 + srow[i]) * K + kk + scg[i]*8, &lds[bo + 0*16384 + sidx[i]*8]);
                gload16(B + (size_t)(rowB0 + srow[i]) * K + kk + scg[i]*8, &lds[bo + 1*16384 + sidx[i]*8]);
            }
            asm volatile("s_waitcnt vmcnt(8)" ::: "memory");
        } else {
            asm volatile("s_waitcnt vmcnt(0)" ::: "memory");
        }
        __builtin_amdgcn_s_barrier();
        __builtin_amdgcn_sched_barrier(0);

        const char* lA = (const char*)&lds[(buf*2 + 0) * 16384];
        const char* lB = (const char*)&lds[(buf*2 + 1) * 16384];

        bf16x8 bfrag[2][4];
        #pragma unroll
        for (int kh = 0; kh < 2; kh++)
            #pragma unroll
            for (int ni = 0; ni < 4; ni++){
                int row = wc*64 + ni*16 + laneRow;
                int raw = row*128 + kh*64 + (laneK<<1);
                bfrag[kh][ni] = *(const bf16x8*)(lB + (raw ^ ((row & 7) << 4)));
            }

        __builtin_amdgcn_s_setprio(1);
        #pragma unroll
        for (int mi = 0; mi < 8; mi++){
            int row = wr*128 + mi*16 + laneRow;
            int mask = (row & 7) << 4;
            int raw0 = row*128 + (laneK<<1);
            bf16x8 a0 = *(const bf16x8*)(lA + (raw0 ^ mask));
            bf16x8 a1 = *(const bf16x8*)(lA + ((raw0 + 64) ^ mask));
            #pragma unroll
            for (int ni = 0; ni < 4; ni++)
                acc[mi][ni] = __builtin_amdgcn_mfma_f32_16x16x32_bf16(a0, bfrag[0][ni], acc[mi][ni], 0, 0, 0);
            #pragma unroll
            for (int ni = 0; ni < 4; ni++)
                acc[mi][ni] = __builtin_amdgcn_mfma_f32_16x16x32_bf16(a1, bfrag[1][ni], acc[mi][ni], 0, 0, 0);
        }
        __builtin_amdgcn_s_setprio(0);
    }

    const int rowBase = rowA0 + wr*128;
    const int colBase = rowB0 + wc*64;
    #pragma unroll
    for (int mi = 0; mi < 8; mi++){
        #pragma unroll
        for (int ni = 0; ni < 4; ni++){
            f32x4 a = acc[mi][ni];
            const int cc = colBase + ni*16 + laneRow;
            const int rr = rowBase + mi*16 + ((lane >> 4) << 2);
            #pragma unroll
            for (int r = 0; r < 4; r++)
                C[(size_t)(rr + r) * ldc + cc] = f2bf(a[r]);
        }
    }
}

// ======================= verified 128^2 GEMM machinery ======================
template<int OF32>
__device__ __forceinline__ void gemm_body(
    const u16* __restrict__ A, const u16* __restrict__ B, void* __restrict__ Cv,
    int K, int ldc, int rowA0, int rowB0, float scale,
    u16* lA, u16* lB)
{
    const int t = threadIdx.x, lane = t & 63, w = t >> 6;
    const int wr = w >> 1, wc = w & 1;

    f32x4 acc[4][4];
    #pragma unroll
    for (int i = 0; i < 4; i++)
        #pragma unroll
        for (int j = 0; j < 4; j++) acc[i][j] = (f32x4){0.f,0.f,0.f,0.f};

    const int r0 = t >> 2,         c0 = (t & 3) << 3;
    const int r1 = (t + 256) >> 2, c1 = ((t + 256) & 3) << 3;
    const int laneRow = lane & 15, laneK = (lane >> 4) << 3;

    const int nK = K >> 5;
    for (int kt = 0; kt < nK; ++kt){
        const int kk = kt << 5;
        gload16(A + (size_t)(rowA0 + r0) * K + kk + c0, &lA[t * 8]);
        gload16(B + (size_t)(rowB0 + r0) * K + kk + c0, &lB[t * 8]);
        gload16(A + (size_t)(rowA0 + r1) * K + kk + c1, &lA[(t + 256) * 8]);
        gload16(B + (size_t)(rowB0 + r1) * K + kk + c1, &lB[(t + 256) * 8]);
        __syncthreads();

        bf16x8 af[4], bfv[4];
        #pragma unroll
        for (int mi = 0; mi < 4; mi++)
            af[mi] = *(const bf16x8*)&lA[(wr*64 + mi*16 + laneRow) * 32 + laneK];
        #pragma unroll
        for (int ni = 0; ni < 4; ni++)
            bfv[ni] = *(const bf16x8*)&lB[(wc*64 + ni*16 + laneRow) * 32 + laneK];

        #pragma unroll
        for (int mi = 0; mi < 4; mi++)
            #pragma unroll
            for (int ni = 0; ni < 4; ni++)
                acc[mi][ni] = __builtin_amdgcn_mfma_f32_16x16x32_bf16(af[mi], bfv[ni], acc[mi][ni], 0, 0, 0);
        __syncthreads();
    }

    const int rowBase = rowA0 + wr*64;
    const int colBase = rowB0 + wc*64;
    #pragma unroll
    for (int mi = 0; mi < 4; mi++){
        #pragma unroll
        for (int ni = 0; ni < 4; ni++){
            f32x4 a = acc[mi][ni];
            const int cc = colBase + ni*16 + laneRow;
            const int rr = rowBase + mi*16 + ((lane >> 4) << 2);
            #pragma unroll
            for (int r = 0; r < 4; r++){
                const size_t idx = (size_t)(rr + r) * ldc + cc;
                float v = a[r] * scale;
                if (OF32) ((float*)Cv)[idx] = v;
                else      ((u16*)Cv)[idx]  = f2bf(v);
            }
        }
    }
}

template<int OF32>
__global__ __launch_bounds__(256) void gemm_b16(
    const u16* __restrict__ A, const u16* __restrict__ B, void* __restrict__ Cv,
    int K, int ldc, long aBatch, long bBatch, long cBatch, float scale)
{
    __shared__ u16 lA[128*32];
    __shared__ u16 lB[128*32];
    const int b = blockIdx.z;
    const u16* Ab = A + (size_t)b * aBatch;
    const u16* Bb = B + (size_t)b * bBatch;
    void* Cb = OF32 ? (void*)((float*)Cv + (size_t)b * cBatch)
                    : (void*)((u16*)Cv  + (size_t)b * cBatch);
    gemm_body<OF32>(Ab, Bb, Cb, K, ldc, blockIdx.y * 128, blockIdx.x * 128, scale, lA, lB);
}

// gated redo of mk+xq (runs only if vfy flagged): z 0..31 mk, z 32..39 xq
__global__ __launch_bounds__(256) void proj_redo(
    const u32* __restrict__ flag,
    const u16* __restrict__ mem16, const u16* __restrict__ wk16, u16* __restrict__ mk16,
    const u16* __restrict__ in16,  const u16* __restrict__ wq16, u16* __restrict__ xq16)
{
    if (*flag == 0) return;
    __shared__ u16 lA[128*32];
    __shared__ u16 lB[128*32];
    if (blockIdx.z < 32)
        gemm_body<0>(mem16, wk16, mk16, 4096, 4096, blockIdx.z * 128, blockIdx.x * 128, 1.0f, lA, lB);
    else
        gemm_body<0>(in16, wq16, xq16, 4096, 4096, (blockIdx.z - 32) * 128, blockIdx.x * 128, 1.0f, lA, lB);
}

__global__ void flag_init(u32* f){ if (threadIdx.x == 0) *f = 0; }

// wave-parallel sample verify: 1024 samples (768 mk + 256 xq), one wave each.
// 64 blocks x 256 thr = 1024 waves; lane-strided u16x8 loads + shfl reduce.
__global__ __launch_bounds__(256) void vfy_proj(
    const u16* __restrict__ mem16, const u16* __restrict__ wk16, const u16* __restrict__ mk16,
    const u16* __restrict__ in16,  const u16* __restrict__ wq16, const u16* __restrict__ xq16,
    u32* __restrict__ flag)
{
    const int wgl = blockIdx.x * 4 + (threadIdx.x >> 6);   // wave id 0..1023
    const int lane = threadIdx.x & 63;
    const u16 *a, *b, *c;
    int row, col;
    if (wgl < 768){
        row = ((wgl * 331 + 17) & 4095);
        col = ((wgl * 173 + 5) & 4095);
        a = mem16 + (size_t)row * 4096; b = wk16 + (size_t)col * 4096;
        c = mk16;
    } else {
        row = ((wgl * 89 + 3) & 1023);
        col = ((wgl * 211 + 9) & 4095);
        a = in16 + (size_t)row * 4096; b = wq16 + (size_t)col * 4096;
        c = xq16;
    }
    float s = 0.f;
    #pragma unroll
    for (int i = 0; i < 8; i++){
        const int o = (i * 64 + lane) * 8;
        u16x8 av = *(const u16x8*)(a + o);
        u16x8 bv = *(const u16x8*)(b + o);
        #pragma unroll
        for (int j = 0; j < 8; j++) s += bf2f(av[j]) * bf2f(bv[j]);
    }
    #pragma unroll
    for (int off = 32; off; off >>= 1) s += __shfl_xor(s, off, 64);
    if (lane == 0){
        if (fabsf(s - bf2f(c[(size_t)row * 4096 + col])) > 0.05f) atomicOr(flag, 1u);
    }
}

// ============================ aux kernels ==================================
__global__ __launch_bounds__(256) void cvt_all(
    const float* __restrict__ m, const float* __restrict__ in,
    const float* __restrict__ q, const float* __restrict__ k,
    u16* __restrict__ m16, u16* __restrict__ in16,
    u16* __restrict__ q16, u16* __restrict__ k16)
{
    const long N0 = 2097152, N1 = N0 + 524288, N2 = N1 + 2097152, N3 = N2 + 2097152;
    for (long g = (long)blockIdx.x * 256 + threadIdx.x; g < N3; g += (long)gridDim.x * 256){
        const float* src; u16* dst; long o;
        if      (g < N0){ src = m;  dst = m16;  o = g; }
        else if (g < N1){ src = in; dst = in16; o = g - N0; }
        else if (g < N2){ src = q;  dst = q16;  o = g - N1; }
        else            { src = k;  dst = k16;  o = g - N2; }
        f32x4 a = *(const f32x4*)(src + o*8);
        f32x4 b = *(const f32x4*)(src + o*8 + 4);
        u16x8 v;
        #pragma unroll
        for (int j = 0; j < 4; j++){ v[j] = ftrunc_bf(a[j]); v[j+4] = ftrunc_bf(b[j]); }
        *(u16x8*)(dst + o*8) = v;
    }
}

__global__ __launch_bounds__(256) void transpose_u16(
    const u16* __restrict__ in, u16* __restrict__ out)
{
    __shared__ u16 tile[64][65];
    const size_t bi = (size_t)blockIdx.z * 2048 * 4096;
    const size_t bo = (size_t)blockIdx.z * 4096 * 2048;
    const int c0 = blockIdx.x * 64;
    const int r0 = blockIdx.y * 64;
    const int x = threadIdx.x & 63, y = threadIdx.x >> 6;
    #pragma unroll
    for (int i = 0; i < 16; i++){
        int r = y + i*4;
        tile[r][x] = in[bi + (size_t)(r0 + r) * 4096 + c0 + x];
    }
    __syncthreads();
    #pragma unroll
    for (int i = 0; i < 16; i++){
        int c = y + i*4;
        out[bo + (size_t)(c0 + c) * 2048 + r0 + x] = tile[x][c];
    }
}

__device__ __forceinline__ u32 shfl_u32(u32 v, int srcx){ return (u32)__shfl_xor((int)v, srcx, 64); }
__device__ __forceinline__ u64 shflxor64(u64 x, int off){
    u32 lo = (u32)x, hi = (u32)(x >> 32);
    lo = shfl_u32(lo, off); hi = shfl_u32(hi, off);
    return (((u64)hi) << 32) | lo;
}

__global__ __launch_bounds__(256) void softmax_argmax16(
    const u16* __restrict__ sc16, u16* __restrict__ probs,
    float* __restrict__ dout, const int* __restrict__ segp)
{
    const int row = blockIdx.x;
    const u16* s = sc16 + (size_t)row * 2048;
    u16* p = probs + (size_t)row * 2048;
    const int t = threadIdx.x, lane = t & 63, w = t >> 6;

    u16x8 rv = *(const u16x8*)(s + (size_t)t * 8);
    float v[8];
    #pragma unroll
    for (int j = 0; j < 8; j++) v[j] = bf2f(rv[j]);

    float mx = v[0];
    #pragma unroll
    for (int j = 1; j < 8; j++) mx = fmaxf(mx, v[j]);
    #pragma unroll
    for (int off = 32; off; off >>= 1) mx = fmaxf(mx, __shfl_xor(mx, off, 64));
    __shared__ float smax[4];
    if (lane == 0) smax[w] = mx;
    __syncthreads();
    mx = fmaxf(fmaxf(smax[0], smax[1]), fmaxf(smax[2], smax[3]));

    float e[8]; float sum = 0.f;
    #pragma unroll
    for (int j = 0; j < 8; j++){ e[j] = expf(v[j] - mx); sum += e[j]; }
    #pragma unroll
    for (int off = 32; off; off >>= 1) sum += __shfl_xor(sum, off, 64);
    __shared__ float ssum[4];
    if (lane == 0) ssum[w] = sum;
    __syncthreads();
    sum = ssum[0] + ssum[1] + ssum[2] + ssum[3];

    u16x8 pv;
    u64 best = 0ull;
    #pragma unroll
    for (int j = 0; j < 8; j++){
        u16 pb = f2bf(e[j] / sum);
        pv[j] = pb;
        u64 key = (((u64)pb) << 32) | (u32)(0x7FFFFFFF - (t*8 + j));
        if (key > best) best = key;
    }
    *(u16x8*)(p + (size_t)t * 8) = pv;

    #pragma unroll
    for (int off = 32; off; off >>= 1){
        u64 o = shflxor64(best, off);
        if (o > best) best = o;
    }
    __shared__ u64 sb[4];
    if (lane == 0) sb[w] = best;
    __syncthreads();
    if (t == 0){
        u64 bb = sb[0];
        if (sb[1] > bb) bb = sb[1];
        if (sb[2] > bb) bb = sb[2];
        if (sb[3] > bb) bb = sb[3];
        int idx = 0x7FFFFFFF - (int)(bb & 0xFFFFFFFFu);
        float hv = (float)(segp[0] - idx);
        dout[4194304 + row] = hv;
        if (row == 0) dout[4195328] = (hv < 4.0f) ? 1.0f : 0.0f;
    }
}

// ====================== FALLBACK KERNELS (R10 verbatim) =====================
template<int F32IN, int OF32>
__global__ __launch_bounds__(256) void gemm_bt(
    const void* __restrict__ Av, const void* __restrict__ Bv, void* __restrict__ Cv,
    int K, int ldc, float scale)
{
    __shared__ u16 lA[128*32];
    __shared__ u16 lB[128*32];
    const int rowA0 = blockIdx.y * 128;
    const int rowB0 = blockIdx.x * 128;
    const int t = threadIdx.x, lane = t & 63, w = t >> 6;
    const int wr = w >> 1, wc = w & 1;

    f32x4 acc[4][4];
    #pragma unroll
    for (int i = 0; i < 4; i++)
        #pragma unroll
        for (int j = 0; j < 4; j++) acc[i][j] = (f32x4){0.f,0.f,0.f,0.f};

    const int r0 = t >> 2,         c0 = (t & 3) << 3;
    const int r1 = (t + 256) >> 2, c1 = ((t + 256) & 3) << 3;
    const int laneRow = lane & 15, laneK = (lane >> 4) << 3;

    const int nK = K >> 5;
    for (int kt = 0; kt < nK; ++kt){
        const int kk = kt << 5;
        if (F32IN){
            const float* Af = (const float*)Av;
            const float* Bf = (const float*)Bv;
            f32x4 a00 = *(const f32x4*)&Af[(size_t)(rowA0 + r0) * K + kk + c0];
            f32x4 a01 = *(const f32x4*)&Af[(size_t)(rowA0 + r0) * K + kk + c0 + 4];
            f32x4 a10 = *(const f32x4*)&Af[(size_t)(rowA0 + r1) * K + kk + c1];
            f32x4 a11 = *(const f32x4*)&Af[(size_t)(rowA0 + r1) * K + kk + c1 + 4];
            f32x4 b00 = *(const f32x4*)&Bf[(size_t)(rowB0 + r0) * K + kk + c0];
            f32x4 b01 = *(const f32x4*)&Bf[(size_t)(rowB0 + r0) * K + kk + c0 + 4];
            f32x4 b10 = *(const f32x4*)&Bf[(size_t)(rowB0 + r1) * K + kk + c1];
            f32x4 b11 = *(const f32x4*)&Bf[(size_t)(rowB0 + r1) * K + kk + c1 + 4];
            u16x8 ua0, ua1, ub0, ub1;
            #pragma unroll
            for (int j = 0; j < 4; j++){
                ua0[j] = ftrunc_bf(a00[j]); ua0[j+4] = ftrunc_bf(a01[j]);
                ua1[j] = ftrunc_bf(a10[j]); ua1[j+4] = ftrunc_bf(a11[j]);
                ub0[j] = ftrunc_bf(b00[j]); ub0[j+4] = ftrunc_bf(b01[j]);
                ub1[j] = ftrunc_bf(b10[j]); ub1[j+4] = ftrunc_bf(b11[j]);
            }
            __syncthreads();
            *(u16x8*)&lA[(size_t)t * 8]         = ua0;
            *(u16x8*)&lA[(size_t)(t + 256) * 8] = ua1;
            *(u16x8*)&lB[(size_t)t * 8]         = ub0;
            *(u16x8*)&lB[(size_t)(t + 256) * 8] = ub1;
            __syncthreads();
        } else {
            const u16* Au = (const u16*)Av;
            const u16* Bu = (const u16*)Bv;
            gload16(Au + (size_t)(rowA0 + r0) * K + kk + c0, &lA[t * 8]);
            gload16(Bu + (size_t)(rowB0 + r0) * K + kk + c0, &lB[t * 8]);
            gload16(Au + (size_t)(rowA0 + r1) * K + kk + c1, &lA[(t + 256) * 8]);
            gload16(Bu + (size_t)(rowB0 + r1) * K + kk + c1, &lB[(t + 256) * 8]);
            __syncthreads();
        }

        bf16x8 af[4], bfv[4];
        #pragma unroll
        for (int mi = 0; mi < 4; mi++)
            af[mi] = *(const bf16x8*)&lA[(wr*64 + mi*16 + laneRow) * 32 + laneK];
        #pragma unroll
        for (int ni = 0; ni < 4; ni++)
            bfv[ni] = *(const bf16x8*)&lB[(wc*64 + ni*16 + laneRow) * 32 + laneK];

        #pragma unroll
        for (int mi = 0; mi < 4; mi++)
            #pragma unroll
            for (int ni = 0; ni < 4; ni++)
                acc[mi][ni] = __builtin_amdgcn_mfma_f32_16x16x32_bf16(af[mi], bfv[ni], acc[mi][ni], 0, 0, 0);
        if (!F32IN) __syncthreads();
    }

    const int rowBase = rowA0 + wr*64;
    const int colBase = rowB0 + wc*64;
    #pragma unroll
    for (int mi = 0; mi < 4; mi++){
        #pragma unroll
        for (int ni = 0; ni < 4; ni++){
            f32x4 a = acc[mi][ni];
            const int cc = colBase + ni*16 + laneRow;
            const int rr = rowBase + mi*16 + ((lane >> 4) << 2);
            #pragma unroll
            for (int r = 0; r < 4; r++){
                const size_t idx = (size_t)(rr + r) * ldc + cc;
                float v = a[r] * scale;
                if (OF32) ((float*)Cv)[idx] = v;
                else      ((u16*)Cv)[idx]  = f2bf(v);
            }
        }
    }
}

__global__ __launch_bounds__(256) void transpose_f2b(
    const float* __restrict__ in, u16* __restrict__ out)
{
    __shared__ u16 tile[64][65];
    const int c0 = blockIdx.x * 64;
    const int r0 = blockIdx.y * 64;
    const int x = threadIdx.x & 63, y = threadIdx.x >> 6;
    #pragma unroll
    for (int i = 0; i < 16; i++){
        int r = y + i*4;
        tile[r][x] = ftrunc_bf(in[(size_t)(r0 + r) * 4096 + c0 + x]);
    }
    __syncthreads();
    #pragma unroll
    for (int i = 0; i < 16; i++){
        int c = y + i*4;
        out[(size_t)(c0 + c) * 2048 + r0 + x] = tile[x][c];
    }
}

// ===========================================================================
extern "C" void kernel_launch(void* const* d_in, const int* in_sizes, int n_in,
                              void* d_out, int out_size, void* d_ws, size_t ws_size,
                              hipStream_t stream)
{
    const float* memory = (const float*)d_in[0];   // [2][2048][4096] f32 (bf16-valued)
    const float* inputs = (const float*)d_in[1];   // [2][512][4096]
    const float* wq     = (const float*)d_in[2];   // [4096][4096]
    const float* wk     = (const float*)d_in[3];   // [4096][4096]
    const int*   seg    = (const int*)d_in[4];
    float* out = (float*)d_out;

    char* ws = (char*)d_ws;
    dim3 blk(256);

    if (ws_size >= (152ull << 20)){
        // ---------------- FAST PATH ----------------
        u16* mem16 = (u16*)(ws);                        // [4096][4096] (both batches)
        u16* in16  = (u16*)(ws + 33554432);             // [1024][4096]
        u16* wq16  = (u16*)(ws + 41943040);
        u16* wk16  = (u16*)(ws + 75497472);
        u16* xq16  = (u16*)(ws + 109051904);
        u16* mk16  = (u16*)(ws + 117440512);            // [4096][4096]; memT later
        u16* sc16  = (u16*)(ws + 150994944);
        u16* pr    = (u16*)(ws + 155189248);
        u16* mt    = mk16;
        u32* flag  = (u32*)sc16;                        // free until scores GEMM

        cvt_all<<<dim3(4096), blk, 0, stream>>>(memory, inputs, wq, wk,
                                                mem16, in16, wq16, wk16);

        // mk (256 blk) + xq (64 blk) fused on the 8-phase 256^2 kernel
        gemm8ph<<<dim3(320), dim3(512), 131072, stream>>>(mem16, wk16, mk16,
                                                          in16, wq16, xq16);

        flag_init<<<1, 64, 0, stream>>>(flag);
        vfy_proj<<<dim3(64), blk, 0, stream>>>(mem16, wk16, mk16, in16, wq16, xq16, flag);
        proj_redo<<<dim3(32, 1, 40), blk, 0, stream>>>(flag, mem16, wk16, mk16,
                                                       in16, wq16, xq16);

        // scores (overwrites flag region — after redo)
        gemm_b16<0><<<dim3(16, 4, 2), blk, 0, stream>>>(xq16, mk16, sc16, 4096, 2048,
                                                        512L*4096, 2048L*4096, 512L*2048,
                                                        0.015625f);
        softmax_argmax16<<<dim3(1024), blk, 0, stream>>>(sc16, pr, out, seg);

        transpose_u16<<<dim3(64, 32, 2), blk, 0, stream>>>(mem16, mt);
        gemm_b16<1><<<dim3(32, 4, 2), blk, 0, stream>>>(pr, mt, out, 2048, 4096,
                                                        512L*2048, 4096L*2048, 512L*4096,
                                                        1.0f);
    } else {
        // ---------------- FALLBACK: R10 (passing) ----------------
        u16* xq16 = (u16*)(ws);
        u16* mk16 = (u16*)(ws + (8u<<20));
        u16* sc16 = (u16*)(ws + (24u<<20));
        u16* pr   = (u16*)(ws + (28u<<20));

        gemm_bt<1,0><<<dim3(32, 8, 1), blk, 0, stream>>>(inputs, wq, xq16, 4096, 4096, 1.0f);
        for (int b = 0; b < 2; ++b){
            const float* memb = memory + (size_t)b * 2048 * 4096;
            gemm_bt<1,0><<<dim3(32, 16, 1), blk, 0, stream>>>(memb, wk, mk16, 4096, 4096, 1.0f);
            gemm_bt<0,0><<<dim3(16, 4, 1), blk, 0, stream>>>(xq16 + (size_t)b*512*4096, mk16,
                                                             sc16 + (size_t)b*512*2048,
                                                             4096, 2048, 0.015625f);
        }
        softmax_argmax16<<<dim3(1024), blk, 0, stream>>>(sc16, pr, out, seg);
        for (int b = 0; b < 2; ++b){
            const float* memb = memory + (size_t)b * 2048 * 4096;
            transpose_f2b<<<dim3(64, 32, 1), blk, 0, stream>>>(memb, mk16);
            gemm_bt<0,1><<<dim3(32, 4, 1), blk, 0, stream>>>(pr + (size_t)b*512*2048, mk16,
                                                             out + (size_t)b*512*4096,
                                                             2048, 4096, 1.0f);
        }
    }
}

// Round 15
// 420.747 us; speedup vs baseline: 1.3402x; 1.0039x over previous
//
#include <hip/hip_runtime.h>

typedef unsigned short u16;
typedef unsigned int   u32;
typedef unsigned long long u64;
typedef __attribute__((ext_vector_type(8))) short bf16x8;
typedef __attribute__((ext_vector_type(8))) unsigned short u16x8;
typedef __attribute__((ext_vector_type(4))) float f32x4;

__device__ __forceinline__ float bf2f(u16 h){ u32 u = ((u32)h)<<16; return __builtin_bit_cast(float, u); }
__device__ __forceinline__ u16 f2bf(float f){
    u32 u = __builtin_bit_cast(u32, f);
    return (u16)((u + 0x7FFFu + ((u>>16)&1u)) >> 16);   // RNE
}
__device__ __forceinline__ u16 ftrunc_bf(float f){      // exact for bf16-valued f32
    return (u16)(__builtin_bit_cast(u32, f) >> 16);
}

__device__ __forceinline__ void gload16(const void* g, void* l){
    __builtin_amdgcn_global_load_lds((const __attribute__((address_space(1))) void*)g,
                                     (__attribute__((address_space(3))) void*)l, 16, 0, 0);
}

// ================= 256x256 8-phase-style GEMM: mk only (256 blocks = 1/CU) =================
// C[4096][4096] = A[4096][4096]@B^T. 512thr = 8 waves (2x4), BK=64, dbuf 128KiB,
// counted vmcnt(8) (full-tile lead), 3-bit row swizzle (conflicts=0, verified R14),
// MFMA split into 4 quadrant phases with per-phase barriers + setprio.
__global__ __launch_bounds__(512, 2) void gemm8ph(
    const u16* __restrict__ A, const u16* __restrict__ B, u16* __restrict__ C)
{
    extern __shared__ u16 lds[];   // 2 bufs x (A 16384 + B 16384) u16 = 128 KiB
    const int K = 4096, ldc = 4096;
    const int t = threadIdx.x;
    const int lane = t & 63, wid = t >> 6;
    const int wr = wid >> 2, wc = wid & 3;
    const int laneRow = lane & 15, laneK = (lane >> 4) << 3;

    // bijective XCD chunk remap (256 blocks, 8 XCDs x 32)
    int bid = blockIdx.x;
    bid = (bid & 7) * 32 + (bid >> 3);
    const int rowA0 = (bid >> 4) * 256, rowB0 = (bid & 15) * 256;

    f32x4 acc[8][4];
    #pragma unroll
    for (int i = 0; i < 8; i++)
        #pragma unroll
        for (int j = 0; j < 4; j++) acc[i][j] = (f32x4){0.f,0.f,0.f,0.f};

    // staging map: linear LDS dest, inverse-swizzled global source (rule #21)
    int sidx[4], srow[4], scg[4];
    #pragma unroll
    for (int i = 0; i < 4; i++){
        int id = i * 512 + t;                 // 0..2047
        sidx[i] = id;
        srow[i] = id >> 3;                    // row 0..255
        scg[i]  = (id & 7) ^ ((id >> 3) & 7); // 16B col-group, 3-bit row XOR
    }

    const int nT = K >> 6;   // 64 K-tiles
    // prologue: stage tile 0 into buf 0
    #pragma unroll
    for (int i = 0; i < 4; i++){
        gload16(A + (size_t)(rowA0 + srow[i]) * K + scg[i]*8, &lds[0*32768 + sidx[i]*8]);
        gload16(B + (size_t)(rowB0 + srow[i]) * K + scg[i]*8, &lds[0*32768 + 16384 + sidx[i]*8]);
    }

    for (int kt = 0; kt < nT; ++kt){
        const int b = kt & 1;
        // prev iteration's q3 barrier guarantees all waves done reading buf b^1
        if (kt + 1 < nT){
            const int kk = (kt + 1) << 6;
            const int bo = (b ^ 1) * 32768;
            #pragma unroll
            for (int i = 0; i < 4; i++){
                gload16(A + (size_t)(rowA0 + srow[i]) * K + kk + scg[i]*8, &lds[bo + sidx[i]*8]);
                gload16(B + (size_t)(rowB0 + srow[i]) * K + kk + scg[i]*8, &lds[bo + 16384 + sidx[i]*8]);
            }
            asm volatile("s_waitcnt vmcnt(8)" ::: "memory");   // tile kt landed (own); kt+1 in flight
        } else {
            asm volatile("s_waitcnt vmcnt(0)" ::: "memory");
        }
        __builtin_amdgcn_s_barrier();            // tile kt visible to all waves
        __builtin_amdgcn_sched_barrier(0);

        const char* lA = (const char*)&lds[b * 32768];
        const char* lB = (const char*)&lds[b * 32768 + 16384];

        bf16x8 bfrag[2][4];
        #pragma unroll
        for (int kh = 0; kh < 2; kh++)
            #pragma unroll
            for (int ni = 0; ni < 4; ni++){
                int row = wc*64 + ni*16 + laneRow;
                int raw = row*128 + kh*64 + (laneK<<1);
                bfrag[kh][ni] = *(const bf16x8*)(lB + (raw ^ ((row & 7) << 4)));
            }

        // 4 quadrant phases: {ds_read 4xb128 -> setprio MFMA x16 -> barrier}
        #pragma unroll
        for (int q = 0; q < 4; ++q){
            bf16x8 af[2][2];
            #pragma unroll
            for (int mm = 0; mm < 2; mm++){
                int mi = q*2 + mm;
                int row = wr*128 + mi*16 + laneRow;
                int mask = (row & 7) << 4;
                int raw0 = row*128 + (laneK<<1);
                af[mm][0] = *(const bf16x8*)(lA + (raw0 ^ mask));
                af[mm][1] = *(const bf16x8*)(lA + ((raw0 + 64) ^ mask));
            }
            __builtin_amdgcn_s_setprio(1);
            #pragma unroll
            for (int mm = 0; mm < 2; mm++){
                int mi = q*2 + mm;
                #pragma unroll
                for (int ni = 0; ni < 4; ni++)
                    acc[mi][ni] = __builtin_amdgcn_mfma_f32_16x16x32_bf16(af[mm][0], bfrag[0][ni], acc[mi][ni], 0, 0, 0);
                #pragma unroll
                for (int ni = 0; ni < 4; ni++)
                    acc[mi][ni] = __builtin_amdgcn_mfma_f32_16x16x32_bf16(af[mm][1], bfrag[1][ni], acc[mi][ni], 0, 0, 0);
            }
            __builtin_amdgcn_s_setprio(0);
            __builtin_amdgcn_s_barrier();        // quadrant lockstep
            __builtin_amdgcn_sched_barrier(0);
        }
    }

    const int rowBase = rowA0 + wr*128;
    const int colBase = rowB0 + wc*64;
    #pragma unroll
    for (int mi = 0; mi < 8; mi++){
        #pragma unroll
        for (int ni = 0; ni < 4; ni++){
            f32x4 a = acc[mi][ni];
            const int cc = colBase + ni*16 + laneRow;
            const int rr = rowBase + mi*16 + ((lane >> 4) << 2);
            #pragma unroll
            for (int r = 0; r < 4; r++)
                C[(size_t)(rr + r) * ldc + cc] = f2bf(a[r]);
        }
    }
}

// ======================= verified 128^2 GEMM machinery ======================
template<int OF32>
__device__ __forceinline__ void gemm_body(
    const u16* __restrict__ A, const u16* __restrict__ B, void* __restrict__ Cv,
    int K, int ldc, int rowA0, int rowB0, float scale,
    u16* lA, u16* lB)
{
    const int t = threadIdx.x, lane = t & 63, w = t >> 6;
    const int wr = w >> 1, wc = w & 1;

    f32x4 acc[4][4];
    #pragma unroll
    for (int i = 0; i < 4; i++)
        #pragma unroll
        for (int j = 0; j < 4; j++) acc[i][j] = (f32x4){0.f,0.f,0.f,0.f};

    const int r0 = t >> 2,         c0 = (t & 3) << 3;
    const int r1 = (t + 256) >> 2, c1 = ((t + 256) & 3) << 3;
    const int laneRow = lane & 15, laneK = (lane >> 4) << 3;

    const int nK = K >> 5;
    for (int kt = 0; kt < nK; ++kt){
        const int kk = kt << 5;
        gload16(A + (size_t)(rowA0 + r0) * K + kk + c0, &lA[t * 8]);
        gload16(B + (size_t)(rowB0 + r0) * K + kk + c0, &lB[t * 8]);
        gload16(A + (size_t)(rowA0 + r1) * K + kk + c1, &lA[(t + 256) * 8]);
        gload16(B + (size_t)(rowB0 + r1) * K + kk + c1, &lB[(t + 256) * 8]);
        __syncthreads();

        bf16x8 af[4], bfv[4];
        #pragma unroll
        for (int mi = 0; mi < 4; mi++)
            af[mi] = *(const bf16x8*)&lA[(wr*64 + mi*16 + laneRow) * 32 + laneK];
        #pragma unroll
        for (int ni = 0; ni < 4; ni++)
            bfv[ni] = *(const bf16x8*)&lB[(wc*64 + ni*16 + laneRow) * 32 + laneK];

        #pragma unroll
        for (int mi = 0; mi < 4; mi++)
            #pragma unroll
            for (int ni = 0; ni < 4; ni++)
                acc[mi][ni] = __builtin_amdgcn_mfma_f32_16x16x32_bf16(af[mi], bfv[ni], acc[mi][ni], 0, 0, 0);
        __syncthreads();
    }

    const int rowBase = rowA0 + wr*64;
    const int colBase = rowB0 + wc*64;
    #pragma unroll
    for (int mi = 0; mi < 4; mi++){
        #pragma unroll
        for (int ni = 0; ni < 4; ni++){
            f32x4 a = acc[mi][ni];
            const int cc = colBase + ni*16 + laneRow;
            const int rr = rowBase + mi*16 + ((lane >> 4) << 2);
            #pragma unroll
            for (int r = 0; r < 4; r++){
                const size_t idx = (size_t)(rr + r) * ldc + cc;
                float v = a[r] * scale;
                if (OF32) ((float*)Cv)[idx] = v;
                else      ((u16*)Cv)[idx]  = f2bf(v);
            }
        }
    }
}

template<int OF32>
__global__ __launch_bounds__(256) void gemm_b16(
    const u16* __restrict__ A, const u16* __restrict__ B, void* __restrict__ Cv,
    int K, int ldc, long aBatch, long bBatch, long cBatch, float scale)
{
    __shared__ u16 lA[128*32];
    __shared__ u16 lB[128*32];
    const int b = blockIdx.z;
    const u16* Ab = A + (size_t)b * aBatch;
    const u16* Bb = B + (size_t)b * bBatch;
    void* Cb = OF32 ? (void*)((float*)Cv + (size_t)b * cBatch)
                    : (void*)((u16*)Cv  + (size_t)b * cBatch);
    gemm_body<OF32>(Ab, Bb, Cb, K, ldc, blockIdx.y * 128, blockIdx.x * 128, scale, lA, lB);
}

// gated redo of mk (runs only if vfy flagged)
__global__ __launch_bounds__(256) void proj_redo(
    const u32* __restrict__ flag,
    const u16* __restrict__ mem16, const u16* __restrict__ wk16, u16* __restrict__ mk16)
{
    if (*flag == 0) return;
    __shared__ u16 lA[128*32];
    __shared__ u16 lB[128*32];
    gemm_body<0>(mem16, wk16, mk16, 4096, 4096, blockIdx.y * 128, blockIdx.x * 128, 1.0f, lA, lB);
}

__global__ void flag_init(u32* f){ if (threadIdx.x == 0) *f = 0; }

// wave-parallel sample verify of mk: 1024 samples, one wave each (64 blocks).
__global__ __launch_bounds__(256) void vfy_mk(
    const u16* __restrict__ mem16, const u16* __restrict__ wk16, const u16* __restrict__ mk16,
    u32* __restrict__ flag)
{
    const int wgl = blockIdx.x * 4 + (threadIdx.x >> 6);   // wave id 0..1023
    const int lane = threadIdx.x & 63;
    const int row = ((wgl * 331 + 17) & 4095);
    const int col = ((wgl * 173 + 5) & 4095);
    const u16* a = mem16 + (size_t)row * 4096;
    const u16* b = wk16 + (size_t)col * 4096;
    float s = 0.f;
    #pragma unroll
    for (int i = 0; i < 8; i++){
        const int o = (i * 64 + lane) * 8;
        u16x8 av = *(const u16x8*)(a + o);
        u16x8 bv = *(const u16x8*)(b + o);
        #pragma unroll
        for (int j = 0; j < 8; j++) s += bf2f(av[j]) * bf2f(bv[j]);
    }
    #pragma unroll
    for (int off = 32; off; off >>= 1) s += __shfl_xor(s, off, 64);
    if (lane == 0){
        if (fabsf(s - bf2f(mk16[(size_t)row * 4096 + col])) > 0.05f) atomicOr(flag, 1u);
    }
}

// ============================ aux kernels ==================================
__global__ __launch_bounds__(256) void cvt_all(
    const float* __restrict__ m, const float* __restrict__ in,
    const float* __restrict__ q, const float* __restrict__ k,
    u16* __restrict__ m16, u16* __restrict__ in16,
    u16* __restrict__ q16, u16* __restrict__ k16)
{
    const long N0 = 2097152, N1 = N0 + 524288, N2 = N1 + 2097152, N3 = N2 + 2097152;
    for (long g = (long)blockIdx.x * 256 + threadIdx.x; g < N3; g += (long)gridDim.x * 256){
        const float* src; u16* dst; long o;
        if      (g < N0){ src = m;  dst = m16;  o = g; }
        else if (g < N1){ src = in; dst = in16; o = g - N0; }
        else if (g < N2){ src = q;  dst = q16;  o = g - N1; }
        else            { src = k;  dst = k16;  o = g - N2; }
        f32x4 a = *(const f32x4*)(src + o*8);
        f32x4 b = *(const f32x4*)(src + o*8 + 4);
        u16x8 v;
        #pragma unroll
        for (int j = 0; j < 4; j++){ v[j] = ftrunc_bf(a[j]); v[j+4] = ftrunc_bf(b[j]); }
        *(u16x8*)(dst + o*8) = v;
    }
}

__global__ __launch_bounds__(256) void transpose_u16(
    const u16* __restrict__ in, u16* __restrict__ out)
{
    __shared__ u16 tile[64][65];
    const size_t bi = (size_t)blockIdx.z * 2048 * 4096;
    const size_t bo = (size_t)blockIdx.z * 4096 * 2048;
    const int c0 = blockIdx.x * 64;
    const int r0 = blockIdx.y * 64;
    const int x = threadIdx.x & 63, y = threadIdx.x >> 6;
    #pragma unroll
    for (int i = 0; i < 16; i++){
        int r = y + i*4;
        tile[r][x] = in[bi + (size_t)(r0 + r) * 4096 + c0 + x];
    }
    __syncthreads();
    #pragma unroll
    for (int i = 0; i < 16; i++){
        int c = y + i*4;
        out[bo + (size_t)(c0 + c) * 2048 + r0 + x] = tile[x][c];
    }
}

__device__ __forceinline__ u32 shfl_u32(u32 v, int srcx){ return (u32)__shfl_xor((int)v, srcx, 64); }
__device__ __forceinline__ u64 shflxor64(u64 x, int off){
    u32 lo = (u32)x, hi = (u32)(x >> 32);
    lo = shfl_u32(lo, off); hi = shfl_u32(hi, off);
    return (((u64)hi) << 32) | lo;
}

__global__ __launch_bounds__(256) void softmax_argmax16(
    const u16* __restrict__ sc16, u16* __restrict__ probs,
    float* __restrict__ dout, const int* __restrict__ segp)
{
    const int row = blockIdx.x;
    const u16* s = sc16 + (size_t)row * 2048;
    u16* p = probs + (size_t)row * 2048;
    const int t = threadIdx.x, lane = t & 63, w = t >> 6;

    u16x8 rv = *(const u16x8*)(s + (size_t)t * 8);
    float v[8];
    #pragma unroll
    for (int j = 0; j < 8; j++) v[j] = bf2f(rv[j]);

    float mx = v[0];
    #pragma unroll
    for (int j = 1; j < 8; j++) mx = fmaxf(mx, v[j]);
    #pragma unroll
    for (int off = 32; off; off >>= 1) mx = fmaxf(mx, __shfl_xor(mx, off, 64));
    __shared__ float smax[4];
    if (lane == 0) smax[w] = mx;
    __syncthreads();
    mx = fmaxf(fmaxf(smax[0], smax[1]), fmaxf(smax[2], smax[3]));

    float e[8]; float sum = 0.f;
    #pragma unroll
    for (int j = 0; j < 8; j++){ e[j] = expf(v[j] - mx); sum += e[j]; }
    #pragma unroll
    for (int off = 32; off; off >>= 1) sum += __shfl_xor(sum, off, 64);
    __shared__ float ssum[4];
    if (lane == 0) ssum[w] = sum;
    __syncthreads();
    sum = ssum[0] + ssum[1] + ssum[2] + ssum[3];

    u16x8 pv;
    u64 best = 0ull;
    #pragma unroll
    for (int j = 0; j < 8; j++){
        u16 pb = f2bf(e[j] / sum);
        pv[j] = pb;
        u64 key = (((u64)pb) << 32) | (u32)(0x7FFFFFFF - (t*8 + j));
        if (key > best) best = key;
    }
    *(u16x8*)(p + (size_t)t * 8) = pv;

    #pragma unroll
    for (int off = 32; off; off >>= 1){
        u64 o = shflxor64(best, off);
        if (o > best) best = o;
    }
    __shared__ u64 sb[4];
    if (lane == 0) sb[w] = best;
    __syncthreads();
    if (t == 0){
        u64 bb = sb[0];
        if (sb[1] > bb) bb = sb[1];
        if (sb[2] > bb) bb = sb[2];
        if (sb[3] > bb) bb = sb[3];
        int idx = 0x7FFFFFFF - (int)(bb & 0xFFFFFFFFu);
        float hv = (float)(segp[0] - idx);
        dout[4194304 + row] = hv;
        if (row == 0) dout[4195328] = (hv < 4.0f) ? 1.0f : 0.0f;
    }
}

// ====================== FALLBACK KERNELS (R10 verbatim) =====================
template<int F32IN, int OF32>
__global__ __launch_bounds__(256) void gemm_bt(
    const void* __restrict__ Av, const void* __restrict__ Bv, void* __restrict__ Cv,
    int K, int ldc, float scale)
{
    __shared__ u16 lA[128*32];
    __shared__ u16 lB[128*32];
    const int rowA0 = blockIdx.y * 128;
    const int rowB0 = blockIdx.x * 128;
    const int t = threadIdx.x, lane = t & 63, w = t >> 6;
    const int wr = w >> 1, wc = w & 1;

    f32x4 acc[4][4];
    #pragma unroll
    for (int i = 0; i < 4; i++)
        #pragma unroll
        for (int j = 0; j < 4; j++) acc[i][j] = (f32x4){0.f,0.f,0.f,0.f};

    const int r0 = t >> 2,         c0 = (t & 3) << 3;
    const int r1 = (t + 256) >> 2, c1 = ((t + 256) & 3) << 3;
    const int laneRow = lane & 15, laneK = (lane >> 4) << 3;

    const int nK = K >> 5;
    for (int kt = 0; kt < nK; ++kt){
        const int kk = kt << 5;
        if (F32IN){
            const float* Af = (const float*)Av;
            const float* Bf = (const float*)Bv;
            f32x4 a00 = *(const f32x4*)&Af[(size_t)(rowA0 + r0) * K + kk + c0];
            f32x4 a01 = *(const f32x4*)&Af[(size_t)(rowA0 + r0) * K + kk + c0 + 4];
            f32x4 a10 = *(const f32x4*)&Af[(size_t)(rowA0 + r1) * K + kk + c1];
            f32x4 a11 = *(const f32x4*)&Af[(size_t)(rowA0 + r1) * K + kk + c1 + 4];
            f32x4 b00 = *(const f32x4*)&Bf[(size_t)(rowB0 + r0) * K + kk + c0];
            f32x4 b01 = *(const f32x4*)&Bf[(size_t)(rowB0 + r0) * K + kk + c0 + 4];
            f32x4 b10 = *(const f32x4*)&Bf[(size_t)(rowB0 + r1) * K + kk + c1];
            f32x4 b11 = *(const f32x4*)&Bf[(size_t)(rowB0 + r1) * K + kk + c1 + 4];
            u16x8 ua0, ua1, ub0, ub1;
            #pragma unroll
            for (int j = 0; j < 4; j++){
                ua0[j] = ftrunc_bf(a00[j]); ua0[j+4] = ftrunc_bf(a01[j]);
                ua1[j] = ftrunc_bf(a10[j]); ua1[j+4] = ftrunc_bf(a11[j]);
                ub0[j] = ftrunc_bf(b00[j]); ub0[j+4] = ftrunc_bf(b01[j]);
                ub1[j] = ftrunc_bf(b10[j]); ub1[j+4] = ftrunc_bf(b11[j]);
            }
            __syncthreads();
            *(u16x8*)&lA[(size_t)t * 8]         = ua0;
            *(u16x8*)&lA[(size_t)(t + 256) * 8] = ua1;
            *(u16x8*)&lB[(size_t)t * 8]         = ub0;
            *(u16x8*)&lB[(size_t)(t + 256) * 8] = ub1;
            __syncthreads();
        } else {
            const u16* Au = (const u16*)Av;
            const u16* Bu = (const u16*)Bv;
            gload16(Au + (size_t)(rowA0 + r0) * K + kk + c0, &lA[t * 8]);
            gload16(Bu + (size_t)(rowB0 + r0) * K + kk + c0, &lB[t * 8]);
            gload16(Au + (size_t)(rowA0 + r1) * K + kk + c1, &lA[(t + 256) * 8]);
            gload16(Bu + (size_t)(rowB0 + r1) * K + kk + c1, &lB[(t + 256) * 8]);
            __syncthreads();
        }

        bf16x8 af[4], bfv[4];
        #pragma unroll
        for (int mi = 0; mi < 4; mi++)
            af[mi] = *(const bf16x8*)&lA[(wr*64 + mi*16 + laneRow) * 32 + laneK];
        #pragma unroll
        for (int ni = 0; ni < 4; ni++)
            bfv[ni] = *(const bf16x8*)&lB[(wc*64 + ni*16 + laneRow) * 32 + laneK];

        #pragma unroll
        for (int mi = 0; mi < 4; mi++)
            #pragma unroll
            for (int ni = 0; ni < 4; ni++)
                acc[mi][ni] = __builtin_amdgcn_mfma_f32_16x16x32_bf16(af[mi], bfv[ni], acc[mi][ni], 0, 0, 0);
        if (!F32IN) __syncthreads();
    }

    const int rowBase = rowA0 + wr*64;
    const int colBase = rowB0 + wc*64;
    #pragma unroll
    for (int mi = 0; mi < 4; mi++){
        #pragma unroll
        for (int ni = 0; ni < 4; ni++){
            f32x4 a = acc[mi][ni];
            const int cc = colBase + ni*16 + laneRow;
            const int rr = rowBase + mi*16 + ((lane >> 4) << 2);
            #pragma unroll
            for (int r = 0; r < 4; r++){
                const size_t idx = (size_t)(rr + r) * ldc + cc;
                float v = a[r] * scale;
                if (OF32) ((float*)Cv)[idx] = v;
                else      ((u16*)Cv)[idx]  = f2bf(v);
            }
        }
    }
}

__global__ __launch_bounds__(256) void transpose_f2b(
    const float* __restrict__ in, u16* __restrict__ out)
{
    __shared__ u16 tile[64][65];
    const int c0 = blockIdx.x * 64;
    const int r0 = blockIdx.y * 64;
    const int x = threadIdx.x & 63, y = threadIdx.x >> 6;
    #pragma unroll
    for (int i = 0; i < 16; i++){
        int r = y + i*4;
        tile[r][x] = ftrunc_bf(in[(size_t)(r0 + r) * 4096 + c0 + x]);
    }
    __syncthreads();
    #pragma unroll
    for (int i = 0; i < 16; i++){
        int c = y + i*4;
        out[(size_t)(c0 + c) * 2048 + r0 + x] = tile[x][c];
    }
}

// ===========================================================================
extern "C" void kernel_launch(void* const* d_in, const int* in_sizes, int n_in,
                              void* d_out, int out_size, void* d_ws, size_t ws_size,
                              hipStream_t stream)
{
    const float* memory = (const float*)d_in[0];   // [2][2048][4096] f32 (bf16-valued)
    const float* inputs = (const float*)d_in[1];   // [2][512][4096]
    const float* wq     = (const float*)d_in[2];   // [4096][4096]
    const float* wk     = (const float*)d_in[3];   // [4096][4096]
    const int*   seg    = (const int*)d_in[4];
    float* out = (float*)d_out;

    char* ws = (char*)d_ws;
    dim3 blk(256);

    if (ws_size >= (152ull << 20)){
        // ---------------- FAST PATH ----------------
        u16* mem16 = (u16*)(ws);                        // [4096][4096] (both batches)
        u16* in16  = (u16*)(ws + 33554432);             // [1024][4096]
        u16* wq16  = (u16*)(ws + 41943040);
        u16* wk16  = (u16*)(ws + 75497472);
        u16* xq16  = (u16*)(ws + 109051904);
        u16* mk16  = (u16*)(ws + 117440512);            // [4096][4096]; memT later
        u16* sc16  = (u16*)(ws + 150994944);
        u16* pr    = (u16*)(ws + 155189248);
        u16* mt    = mk16;
        u32* flag  = (u32*)sc16;                        // free until scores GEMM

        cvt_all<<<dim3(4096), blk, 0, stream>>>(memory, inputs, wq, wk,
                                                mem16, in16, wq16, wk16);

        // mk only on the 8-phase 256^2 kernel: exactly 256 blocks = 1/CU, no tail
        gemm8ph<<<dim3(256), dim3(512), 131072, stream>>>(mem16, wk16, mk16);

        flag_init<<<1, 64, 0, stream>>>(flag);
        vfy_mk<<<dim3(64), blk, 0, stream>>>(mem16, wk16, mk16, flag);
        proj_redo<<<dim3(32, 32, 1), blk, 0, stream>>>(flag, mem16, wk16, mk16);

        // xq on verified 128^2 path (256 blocks)
        gemm_b16<0><<<dim3(32, 8, 1), blk, 0, stream>>>(in16, wq16, xq16, 4096, 4096,
                                                        0L, 0L, 0L, 1.0f);
        // scores (overwrites flag region — after redo)
        gemm_b16<0><<<dim3(16, 4, 2), blk, 0, stream>>>(xq16, mk16, sc16, 4096, 2048,
                                                        512L*4096, 2048L*4096, 512L*2048,
                                                        0.015625f);
        softmax_argmax16<<<dim3(1024), blk, 0, stream>>>(sc16, pr, out, seg);

        transpose_u16<<<dim3(64, 32, 2), blk, 0, stream>>>(mem16, mt);
        gemm_b16<1><<<dim3(32, 4, 2), blk, 0, stream>>>(pr, mt, out, 2048, 4096,
                                                        512L*2048, 4096L*2048, 512L*4096,
                                                        1.0f);
    } else {
        // ---------------- FALLBACK: R10 (passing) ----------------
        u16* xq16 = (u16*)(ws);
        u16* mk16 = (u16*)(ws + (8u<<20));
        u16* sc16 = (u16*)(ws + (24u<<20));
        u16* pr   = (u16*)(ws + (28u<<20));

        gemm_bt<1,0><<<dim3(32, 8, 1), blk, 0, stream>>>(inputs, wq, xq16, 4096, 4096, 1.0f);
        for (int b = 0; b < 2; ++b){
            const float* memb = memory + (size_t)b * 2048 * 4096;
            gemm_bt<1,0><<<dim3(32, 16, 1), blk, 0, stream>>>(memb, wk, mk16, 4096, 4096, 1.0f);
            gemm_bt<0,0><<<dim3(16, 4, 1), blk, 0, stream>>>(xq16 + (size_t)b*512*4096, mk16,
                                                             sc16 + (size_t)b*512*2048,
                                                             4096, 2048, 0.015625f);
        }
        softmax_argmax16<<<dim3(1024), blk, 0, stream>>>(sc16, pr, out, seg);
        for (int b = 0; b < 2; ++b){
            const float* memb = memory + (size_t)b * 2048 * 4096;
            transpose_f2b<<<dim3(64, 32, 1), blk, 0, stream>>>(memb, mk16);
            gemm_bt<0,1><<<dim3(32, 4, 1), blk, 0, stream>>>(pr + (size_t)b*512*2048, mk16,
                                                             out + (size_t)b*512*4096,
                                                             2048, 4096, 1.0f);
        }
    }
}

// Round 16
// 408.402 us; speedup vs baseline: 1.3807x; 1.0302x over previous
//
#include <hip/hip_runtime.h>

typedef unsigned short u16;
typedef unsigned int   u32;
typedef unsigned long long u64;
typedef __attribute__((ext_vector_type(8))) short bf16x8;
typedef __attribute__((ext_vector_type(8))) unsigned short u16x8;
typedef __attribute__((ext_vector_type(4))) float f32x4;

__device__ __forceinline__ float bf2f(u16 h){ u32 u = ((u32)h)<<16; return __builtin_bit_cast(float, u); }
__device__ __forceinline__ u16 f2bf(float f){
    u32 u = __builtin_bit_cast(u32, f);
    return (u16)((u + 0x7FFFu + ((u>>16)&1u)) >> 16);   // RNE
}
__device__ __forceinline__ u16 ftrunc_bf(float f){      // exact for bf16-valued f32
    return (u16)(__builtin_bit_cast(u32, f) >> 16);
}

__device__ __forceinline__ void gload16(const void* g, void* l){
    __builtin_amdgcn_global_load_lds((const __attribute__((address_space(1))) void*)g,
                                     (__attribute__((address_space(3))) void*)l, 16, 0, 0);
}

// ========== 256x256 GEMM, 4-deep ring pipeline (mk only, 256 blocks = 1/CU) ==========
// C[4096][4096] = A@B^T. 512thr = 8 waves (2x4), BK=32, FOUR LDS buffers (128 KiB),
// counted vmcnt(12) => 3 tiles of load lead. Swizzle: chunk ^= (row>>1)&3 both sides.
__global__ __launch_bounds__(512, 2) void gemm8ph(
    const u16* __restrict__ A, const u16* __restrict__ B, u16* __restrict__ C)
{
    extern __shared__ u16 lds[];   // 4 bufs x (A 8192 + B 8192) u16 = 128 KiB
    const int K = 4096, ldc = 4096;
    const int t = threadIdx.x;
    const int lane = t & 63, wid = t >> 6;
    const int wr = wid >> 2, wc = wid & 3;
    const int laneRow = lane & 15, laneK = (lane >> 4) << 3;
    const int laneCk = laneK >> 3;                     // 16B chunk index 0..3

    int bid = blockIdx.x;
    bid = (bid & 7) * 32 + (bid >> 3);                 // bijective XCD remap
    const int rowA0 = (bid >> 4) * 256, rowB0 = (bid & 15) * 256;

    f32x4 acc[8][4];
    #pragma unroll
    for (int i = 0; i < 8; i++)
        #pragma unroll
        for (int j = 0; j < 4; j++) acc[i][j] = (f32x4){0.f,0.f,0.f,0.f};

    // staging: per tile, per thread: 2 A-ids {t, t+512} + 2 B-ids. id -> row=id>>2, chunk=id&3.
    // global source chunk pre-swizzled: chunk ^ ((row>>1)&3)  == (id&3) ^ ((id>>3)&3)
    const int idA0 = t, idA1 = t + 512;
    const int rA0 = idA0 >> 2, cA0 = (idA0 & 3) ^ ((idA0 >> 3) & 3);
    const int rA1 = idA1 >> 2, cA1 = (idA1 & 3) ^ ((idA1 >> 3) & 3);

    const int nT = K >> 5;   // 128 K-tiles of 32

    #define STAGE(kt_) do{                                                            \
        const int _kk = (kt_) << 5;                                                   \
        u16* _b = &lds[((kt_) & 3) * 16384];                                          \
        gload16(A + (size_t)(rowA0 + rA0) * K + _kk + cA0*8, &_b[idA0*8]);            \
        gload16(A + (size_t)(rowA0 + rA1) * K + _kk + cA1*8, &_b[idA1*8]);            \
        gload16(B + (size_t)(rowB0 + rA0) * K + _kk + cA0*8, &_b[8192 + idA0*8]);     \
        gload16(B + (size_t)(rowB0 + rA1) * K + _kk + cA1*8, &_b[8192 + idA1*8]);     \
    } while(0)

    STAGE(0); STAGE(1); STAGE(2);    // prologue: 3 tiles in flight (12 loads)

    for (int kt = 0; kt < nT; ++kt){
        __builtin_amdgcn_s_barrier();     // all waves done reading buf[(kt+3)&3] (tile kt-1)
        if (kt + 3 < nT){
            STAGE(kt + 3);
            asm volatile("s_waitcnt vmcnt(12)" ::: "memory");  // tile kt landed; 3 in flight
        } else if (kt + 2 < nT){
            asm volatile("s_waitcnt vmcnt(8)" ::: "memory");
        } else if (kt + 1 < nT){
            asm volatile("s_waitcnt vmcnt(4)" ::: "memory");
        } else {
            asm volatile("s_waitcnt vmcnt(0)" ::: "memory");
        }
        __builtin_amdgcn_s_barrier();     // tile kt published by all waves
        __builtin_amdgcn_sched_barrier(0);

        const char* lA = (const char*)&lds[(kt & 3) * 16384];
        const char* lB = lA + 16384;

        bf16x8 bfrag[4];
        #pragma unroll
        for (int ni = 0; ni < 4; ni++){
            int row = wc*64 + ni*16 + laneRow;
            bfrag[ni] = *(const bf16x8*)(lB + row*64 + ((laneCk ^ ((row >> 1) & 3)) << 4));
        }

        __builtin_amdgcn_s_setprio(1);
        #pragma unroll
        for (int mi = 0; mi < 8; mi++){
            int row = wr*128 + mi*16 + laneRow;
            bf16x8 a0 = *(const bf16x8*)(lA + row*64 + ((laneCk ^ ((row >> 1) & 3)) << 4));
            #pragma unroll
            for (int ni = 0; ni < 4; ni++)
                acc[mi][ni] = __builtin_amdgcn_mfma_f32_16x16x32_bf16(a0, bfrag[ni], acc[mi][ni], 0, 0, 0);
        }
        __builtin_amdgcn_s_setprio(0);
    }
    #undef STAGE

    const int rowBase = rowA0 + wr*128;
    const int colBase = rowB0 + wc*64;
    #pragma unroll
    for (int mi = 0; mi < 8; mi++){
        #pragma unroll
        for (int ni = 0; ni < 4; ni++){
            f32x4 a = acc[mi][ni];
            const int cc = colBase + ni*16 + laneRow;
            const int rr = rowBase + mi*16 + ((lane >> 4) << 2);
            #pragma unroll
            for (int r = 0; r < 4; r++)
                C[(size_t)(rr + r) * ldc + cc] = f2bf(a[r]);
        }
    }
}

// ======================= verified 128^2 GEMM machinery ======================
template<int OF32>
__device__ __forceinline__ void gemm_body(
    const u16* __restrict__ A, const u16* __restrict__ B, void* __restrict__ Cv,
    int K, int ldc, int rowA0, int rowB0, float scale,
    u16* lA, u16* lB)
{
    const int t = threadIdx.x, lane = t & 63, w = t >> 6;
    const int wr = w >> 1, wc = w & 1;

    f32x4 acc[4][4];
    #pragma unroll
    for (int i = 0; i < 4; i++)
        #pragma unroll
        for (int j = 0; j < 4; j++) acc[i][j] = (f32x4){0.f,0.f,0.f,0.f};

    const int r0 = t >> 2,         c0 = (t & 3) << 3;
    const int r1 = (t + 256) >> 2, c1 = ((t + 256) & 3) << 3;
    const int laneRow = lane & 15, laneK = (lane >> 4) << 3;

    const int nK = K >> 5;
    for (int kt = 0; kt < nK; ++kt){
        const int kk = kt << 5;
        gload16(A + (size_t)(rowA0 + r0) * K + kk + c0, &lA[t * 8]);
        gload16(B + (size_t)(rowB0 + r0) * K + kk + c0, &lB[t * 8]);
        gload16(A + (size_t)(rowA0 + r1) * K + kk + c1, &lA[(t + 256) * 8]);
        gload16(B + (size_t)(rowB0 + r1) * K + kk + c1, &lB[(t + 256) * 8]);
        __syncthreads();

        bf16x8 af[4], bfv[4];
        #pragma unroll
        for (int mi = 0; mi < 4; mi++)
            af[mi] = *(const bf16x8*)&lA[(wr*64 + mi*16 + laneRow) * 32 + laneK];
        #pragma unroll
        for (int ni = 0; ni < 4; ni++)
            bfv[ni] = *(const bf16x8*)&lB[(wc*64 + ni*16 + laneRow) * 32 + laneK];

        #pragma unroll
        for (int mi = 0; mi < 4; mi++)
            #pragma unroll
            for (int ni = 0; ni < 4; ni++)
                acc[mi][ni] = __builtin_amdgcn_mfma_f32_16x16x32_bf16(af[mi], bfv[ni], acc[mi][ni], 0, 0, 0);
        __syncthreads();
    }

    const int rowBase = rowA0 + wr*64;
    const int colBase = rowB0 + wc*64;
    #pragma unroll
    for (int mi = 0; mi < 4; mi++){
        #pragma unroll
        for (int ni = 0; ni < 4; ni++){
            f32x4 a = acc[mi][ni];
            const int cc = colBase + ni*16 + laneRow;
            const int rr = rowBase + mi*16 + ((lane >> 4) << 2);
            #pragma unroll
            for (int r = 0; r < 4; r++){
                const size_t idx = (size_t)(rr + r) * ldc + cc;
                float v = a[r] * scale;
                if (OF32) ((float*)Cv)[idx] = v;
                else      ((u16*)Cv)[idx]  = f2bf(v);
            }
        }
    }
}

template<int OF32>
__global__ __launch_bounds__(256) void gemm_b16(
    const u16* __restrict__ A, const u16* __restrict__ B, void* __restrict__ Cv,
    int K, int ldc, long aBatch, long bBatch, long cBatch, float scale)
{
    __shared__ u16 lA[128*32];
    __shared__ u16 lB[128*32];
    const int b = blockIdx.z;
    const u16* Ab = A + (size_t)b * aBatch;
    const u16* Bb = B + (size_t)b * bBatch;
    void* Cb = OF32 ? (void*)((float*)Cv + (size_t)b * cBatch)
                    : (void*)((u16*)Cv  + (size_t)b * cBatch);
    gemm_body<OF32>(Ab, Bb, Cb, K, ldc, blockIdx.y * 128, blockIdx.x * 128, scale, lA, lB);
}

// ============ 64x128-tile GEMM for scores: full-grid small-M GEMM ============
// C[M][N] = A[M][K] @ B[N][K]^T * scale, bf16 out. 256 thr = 4 waves (2x2),
// wave tile 32x64. BK=32.
__global__ __launch_bounds__(256) void gemm64(
    const u16* __restrict__ A, const u16* __restrict__ B, u16* __restrict__ C,
    int K, int ldc, long aBatch, long bBatch, long cBatch, float scale)
{
    __shared__ u16 lA[64*32];
    __shared__ u16 lB[128*32];
    const int bz = blockIdx.z;
    A += (size_t)bz * aBatch;
    B += (size_t)bz * bBatch;
    C += (size_t)bz * cBatch;
    const int rowA0 = blockIdx.y * 64;
    const int rowB0 = blockIdx.x * 128;
    const int t = threadIdx.x, lane = t & 63, w = t >> 6;
    const int wr = w >> 1, wc = w & 1;
    const int laneRow = lane & 15, laneK = (lane >> 4) << 3;

    f32x4 acc[2][4];
    #pragma unroll
    for (int i = 0; i < 2; i++)
        #pragma unroll
        for (int j = 0; j < 4; j++) acc[i][j] = (f32x4){0.f,0.f,0.f,0.f};

    const int rA = t >> 2,  cA = (t & 3) << 3;          // A: 64x32, 1 load
    const int rB0 = t >> 2, cB0 = (t & 3) << 3;         // B: 128x32, 2 loads
    const int rB1 = (t + 256) >> 2, cB1 = ((t + 256) & 3) << 3;

    const int nK = K >> 5;
    for (int kt = 0; kt < nK; ++kt){
        const int kk = kt << 5;
        gload16(A + (size_t)(rowA0 + rA) * K + kk + cA, &lA[t * 8]);
        gload16(B + (size_t)(rowB0 + rB0) * K + kk + cB0, &lB[t * 8]);
        gload16(B + (size_t)(rowB0 + rB1) * K + kk + cB1, &lB[(t + 256) * 8]);
        __syncthreads();

        bf16x8 af[2], bfv[4];
        #pragma unroll
        for (int mi = 0; mi < 2; mi++)
            af[mi] = *(const bf16x8*)&lA[(wr*32 + mi*16 + laneRow) * 32 + laneK];
        #pragma unroll
        for (int ni = 0; ni < 4; ni++)
            bfv[ni] = *(const bf16x8*)&lB[(wc*64 + ni*16 + laneRow) * 32 + laneK];

        #pragma unroll
        for (int mi = 0; mi < 2; mi++)
            #pragma unroll
            for (int ni = 0; ni < 4; ni++)
                acc[mi][ni] = __builtin_amdgcn_mfma_f32_16x16x32_bf16(af[mi], bfv[ni], acc[mi][ni], 0, 0, 0);
        __syncthreads();
    }

    const int rowBase = rowA0 + wr*32;
    const int colBase = rowB0 + wc*64;
    #pragma unroll
    for (int mi = 0; mi < 2; mi++){
        #pragma unroll
        for (int ni = 0; ni < 4; ni++){
            f32x4 a = acc[mi][ni];
            const int cc = colBase + ni*16 + laneRow;
            const int rr = rowBase + mi*16 + ((lane >> 4) << 2);
            #pragma unroll
            for (int r = 0; r < 4; r++)
                C[(size_t)(rr + r) * ldc + cc] = f2bf(a[r] * scale);
        }
    }
}

// gated redo of mk (runs only if vfy flagged)
__global__ __launch_bounds__(256) void proj_redo(
    const u32* __restrict__ flag,
    const u16* __restrict__ mem16, const u16* __restrict__ wk16, u16* __restrict__ mk16)
{
    if (*flag == 0) return;
    __shared__ u16 lA[128*32];
    __shared__ u16 lB[128*32];
    gemm_body<0>(mem16, wk16, mk16, 4096, 4096, blockIdx.y * 128, blockIdx.x * 128, 1.0f, lA, lB);
}

// wave-parallel sample verify of mk: 256 samples, one wave each (64 blocks).
__global__ __launch_bounds__(256) void vfy_mk(
    const u16* __restrict__ mem16, const u16* __restrict__ wk16, const u16* __restrict__ mk16,
    u32* __restrict__ flag)
{
    const int wgl = blockIdx.x * 4 + (threadIdx.x >> 6);
    const int lane = threadIdx.x & 63;
    const int row = ((wgl * 331 + 17) & 4095);
    const int col = ((wgl * 173 + 5) & 4095);
    const u16* a = mem16 + (size_t)row * 4096;
    const u16* b = wk16 + (size_t)col * 4096;
    float s = 0.f;
    #pragma unroll
    for (int i = 0; i < 8; i++){
        const int o = (i * 64 + lane) * 8;
        u16x8 av = *(const u16x8*)(a + o);
        u16x8 bv = *(const u16x8*)(b + o);
        #pragma unroll
        for (int j = 0; j < 8; j++) s += bf2f(av[j]) * bf2f(bv[j]);
    }
    #pragma unroll
    for (int off = 32; off; off >>= 1) s += __shfl_xor(s, off, 64);
    if (lane == 0){
        if (fabsf(s - bf2f(mk16[(size_t)row * 4096 + col])) > 0.05f) atomicOr(flag, 1u);
    }
}

// ============================ aux kernels ==================================
__global__ __launch_bounds__(256) void cvt_all(
    const float* __restrict__ m, const float* __restrict__ in,
    const float* __restrict__ q, const float* __restrict__ k,
    u16* __restrict__ m16, u16* __restrict__ in16,
    u16* __restrict__ q16, u16* __restrict__ k16, u32* __restrict__ flag)
{
    if (blockIdx.x == 0 && threadIdx.x == 0) *flag = 0;   // fold flag-init
    const long N0 = 2097152, N1 = N0 + 524288, N2 = N1 + 2097152, N3 = N2 + 2097152;
    for (long g = (long)blockIdx.x * 256 + threadIdx.x; g < N3; g += (long)gridDim.x * 256){
        const float* src; u16* dst; long o;
        if      (g < N0){ src = m;  dst = m16;  o = g; }
        else if (g < N1){ src = in; dst = in16; o = g - N0; }
        else if (g < N2){ src = q;  dst = q16;  o = g - N1; }
        else            { src = k;  dst = k16;  o = g - N2; }
        f32x4 a = *(const f32x4*)(src + o*8);
        f32x4 b = *(const f32x4*)(src + o*8 + 4);
        u16x8 v;
        #pragma unroll
        for (int j = 0; j < 4; j++){ v[j] = ftrunc_bf(a[j]); v[j+4] = ftrunc_bf(b[j]); }
        *(u16x8*)(dst + o*8) = v;
    }
}

__global__ __launch_bounds__(256) void transpose_u16(
    const u16* __restrict__ in, u16* __restrict__ out)
{
    __shared__ u16 tile[64][65];
    const size_t bi = (size_t)blockIdx.z * 2048 * 4096;
    const size_t bo = (size_t)blockIdx.z * 4096 * 2048;
    const int c0 = blockIdx.x * 64;
    const int r0 = blockIdx.y * 64;
    const int x = threadIdx.x & 63, y = threadIdx.x >> 6;
    #pragma unroll
    for (int i = 0; i < 16; i++){
        int r = y + i*4;
        tile[r][x] = in[bi + (size_t)(r0 + r) * 4096 + c0 + x];
    }
    __syncthreads();
    #pragma unroll
    for (int i = 0; i < 16; i++){
        int c = y + i*4;
        out[bo + (size_t)(c0 + c) * 2048 + r0 + x] = tile[x][c];
    }
}

__device__ __forceinline__ u32 shfl_u32(u32 v, int srcx){ return (u32)__shfl_xor((int)v, srcx, 64); }
__device__ __forceinline__ u64 shflxor64(u64 x, int off){
    u32 lo = (u32)x, hi = (u32)(x >> 32);
    lo = shfl_u32(lo, off); hi = shfl_u32(hi, off);
    return (((u64)hi) << 32) | lo;
}

__global__ __launch_bounds__(256) void softmax_argmax16(
    const u16* __restrict__ sc16, u16* __restrict__ probs,
    float* __restrict__ dout, const int* __restrict__ segp)
{
    const int row = blockIdx.x;
    const u16* s = sc16 + (size_t)row * 2048;
    u16* p = probs + (size_t)row * 2048;
    const int t = threadIdx.x, lane = t & 63, w = t >> 6;

    u16x8 rv = *(const u16x8*)(s + (size_t)t * 8);
    float v[8];
    #pragma unroll
    for (int j = 0; j < 8; j++) v[j] = bf2f(rv[j]);

    float mx = v[0];
    #pragma unroll
    for (int j = 1; j < 8; j++) mx = fmaxf(mx, v[j]);
    #pragma unroll
    for (int off = 32; off; off >>= 1) mx = fmaxf(mx, __shfl_xor(mx, off, 64));
    __shared__ float smax[4];
    if (lane == 0) smax[w] = mx;
    __syncthreads();
    mx = fmaxf(fmaxf(smax[0], smax[1]), fmaxf(smax[2], smax[3]));

    float e[8]; float sum = 0.f;
    #pragma unroll
    for (int j = 0; j < 8; j++){ e[j] = expf(v[j] - mx); sum += e[j]; }
    #pragma unroll
    for (int off = 32; off; off >>= 1) sum += __shfl_xor(sum, off, 64);
    __shared__ float ssum[4];
    if (lane == 0) ssum[w] = sum;
    __syncthreads();
    sum = ssum[0] + ssum[1] + ssum[2] + ssum[3];

    u16x8 pv;
    u64 best = 0ull;
    #pragma unroll
    for (int j = 0; j < 8; j++){
        u16 pb = f2bf(e[j] / sum);
        pv[j] = pb;
        u64 key = (((u64)pb) << 32) | (u32)(0x7FFFFFFF - (t*8 + j));
        if (key > best) best = key;
    }
    *(u16x8*)(p + (size_t)t * 8) = pv;

    #pragma unroll
    for (int off = 32; off; off >>= 1){
        u64 o = shflxor64(best, off);
        if (o > best) best = o;
    }
    __shared__ u64 sb[4];
    if (lane == 0) sb[w] = best;
    __syncthreads();
    if (t == 0){
        u64 bb = sb[0];
        if (sb[1] > bb) bb = sb[1];
        if (sb[2] > bb) bb = sb[2];
        if (sb[3] > bb) bb = sb[3];
        int idx = 0x7FFFFFFF - (int)(bb & 0xFFFFFFFFu);
        float hv = (float)(segp[0] - idx);
        dout[4194304 + row] = hv;
        if (row == 0) dout[4195328] = (hv < 4.0f) ? 1.0f : 0.0f;
    }
}

// ====================== FALLBACK KERNELS (R10 verbatim) =====================
template<int F32IN, int OF32>
__global__ __launch_bounds__(256) void gemm_bt(
    const void* __restrict__ Av, const void* __restrict__ Bv, void* __restrict__ Cv,
    int K, int ldc, float scale)
{
    __shared__ u16 lA[128*32];
    __shared__ u16 lB[128*32];
    const int rowA0 = blockIdx.y * 128;
    const int rowB0 = blockIdx.x * 128;
    const int t = threadIdx.x, lane = t & 63, w = t >> 6;
    const int wr = w >> 1, wc = w & 1;

    f32x4 acc[4][4];
    #pragma unroll
    for (int i = 0; i < 4; i++)
        #pragma unroll
        for (int j = 0; j < 4; j++) acc[i][j] = (f32x4){0.f,0.f,0.f,0.f};

    const int r0 = t >> 2,         c0 = (t & 3) << 3;
    const int r1 = (t + 256) >> 2, c1 = ((t + 256) & 3) << 3;
    const int laneRow = lane & 15, laneK = (lane >> 4) << 3;

    const int nK = K >> 5;
    for (int kt = 0; kt < nK; ++kt){
        const int kk = kt << 5;
        if (F32IN){
            const float* Af = (const float*)Av;
            const float* Bf = (const float*)Bv;
            f32x4 a00 = *(const f32x4*)&Af[(size_t)(rowA0 + r0) * K + kk + c0];
            f32x4 a01 = *(const f32x4*)&Af[(size_t)(rowA0 + r0) * K + kk + c0 + 4];
            f32x4 a10 = *(const f32x4*)&Af[(size_t)(rowA0 + r1) * K + kk + c1];
            f32x4 a11 = *(const f32x4*)&Af[(size_t)(rowA0 + r1) * K + kk + c1 + 4];
            f32x4 b00 = *(const f32x4*)&Bf[(size_t)(rowB0 + r0) * K + kk + c0];
            f32x4 b01 = *(const f32x4*)&Bf[(size_t)(rowB0 + r0) * K + kk + c0 + 4];
            f32x4 b10 = *(const f32x4*)&Bf[(size_t)(rowB0 + r1) * K + kk + c1];
            f32x4 b11 = *(const f32x4*)&Bf[(size_t)(rowB0 + r1) * K + kk + c1 + 4];
            u16x8 ua0, ua1, ub0, ub1;
            #pragma unroll
            for (int j = 0; j < 4; j++){
                ua0[j] = ftrunc_bf(a00[j]); ua0[j+4] = ftrunc_bf(a01[j]);
                ua1[j] = ftrunc_bf(a10[j]); ua1[j+4] = ftrunc_bf(a11[j]);
                ub0[j] = ftrunc_bf(b00[j]); ub0[j+4] = ftrunc_bf(b01[j]);
                ub1[j] = ftrunc_bf(b10[j]); ub1[j+4] = ftrunc_bf(b11[j]);
            }
            __syncthreads();
            *(u16x8*)&lA[(size_t)t * 8]         = ua0;
            *(u16x8*)&lA[(size_t)(t + 256) * 8] = ua1;
            *(u16x8*)&lB[(size_t)t * 8]         = ub0;
            *(u16x8*)&lB[(size_t)(t + 256) * 8] = ub1;
            __syncthreads();
        } else {
            const u16* Au = (const u16*)Av;
            const u16* Bu = (const u16*)Bv;
            gload16(Au + (size_t)(rowA0 + r0) * K + kk + c0, &lA[t * 8]);
            gload16(Bu + (size_t)(rowB0 + r0) * K + kk + c0, &lB[t * 8]);
            gload16(Au + (size_t)(rowA0 + r1) * K + kk + c1, &lA[(t + 256) * 8]);
            gload16(Bu + (size_t)(rowB0 + r1) * K + kk + c1, &lB[(t + 256) * 8]);
            __syncthreads();
        }

        bf16x8 af[4], bfv[4];
        #pragma unroll
        for (int mi = 0; mi < 4; mi++)
            af[mi] = *(const bf16x8*)&lA[(wr*64 + mi*16 + laneRow) * 32 + laneK];
        #pragma unroll
        for (int ni = 0; ni < 4; ni++)
            bfv[ni] = *(const bf16x8*)&lB[(wc*64 + ni*16 + laneRow) * 32 + laneK];

        #pragma unroll
        for (int mi = 0; mi < 4; mi++)
            #pragma unroll
            for (int ni = 0; ni < 4; ni++)
                acc[mi][ni] = __builtin_amdgcn_mfma_f32_16x16x32_bf16(af[mi], bfv[ni], acc[mi][ni], 0, 0, 0);
        if (!F32IN) __syncthreads();
    }

    const int rowBase = rowA0 + wr*64;
    const int colBase = rowB0 + wc*64;
    #pragma unroll
    for (int mi = 0; mi < 4; mi++){
        #pragma unroll
        for (int ni = 0; ni < 4; ni++){
            f32x4 a = acc[mi][ni];
            const int cc = colBase + ni*16 + laneRow;
            const int rr = rowBase + mi*16 + ((lane >> 4) << 2);
            #pragma unroll
            for (int r = 0; r < 4; r++){
                const size_t idx = (size_t)(rr + r) * ldc + cc;
                float v = a[r] * scale;
                if (OF32) ((float*)Cv)[idx] = v;
                else      ((u16*)Cv)[idx]  = f2bf(v);
            }
        }
    }
}

__global__ __launch_bounds__(256) void transpose_f2b(
    const float* __restrict__ in, u16* __restrict__ out)
{
    __shared__ u16 tile[64][65];
    const int c0 = blockIdx.x * 64;
    const int r0 = blockIdx.y * 64;
    const int x = threadIdx.x & 63, y = threadIdx.x >> 6;
    #pragma unroll
    for (int i = 0; i < 16; i++){
        int r = y + i*4;
        tile[r][x] = ftrunc_bf(in[(size_t)(r0 + r) * 4096 + c0 + x]);
    }
    __syncthreads();
    #pragma unroll
    for (int i = 0; i < 16; i++){
        int c = y + i*4;
        out[(size_t)(c0 + c) * 2048 + r0 + x] = tile[x][c];
    }
}

// ===========================================================================
extern "C" void kernel_launch(void* const* d_in, const int* in_sizes, int n_in,
                              void* d_out, int out_size, void* d_ws, size_t ws_size,
                              hipStream_t stream)
{
    const float* memory = (const float*)d_in[0];   // [2][2048][4096] f32 (bf16-valued)
    const float* inputs = (const float*)d_in[1];   // [2][512][4096]
    const float* wq     = (const float*)d_in[2];   // [4096][4096]
    const float* wk     = (const float*)d_in[3];   // [4096][4096]
    const int*   seg    = (const int*)d_in[4];
    float* out = (float*)d_out;

    char* ws = (char*)d_ws;
    dim3 blk(256);

    if (ws_size >= (152ull << 20)){
        // ---------------- FAST PATH ----------------
        u16* mem16 = (u16*)(ws);                        // [4096][4096] (both batches)
        u16* in16  = (u16*)(ws + 33554432);             // [1024][4096]
        u16* wq16  = (u16*)(ws + 41943040);
        u16* wk16  = (u16*)(ws + 75497472);
        u16* xq16  = (u16*)(ws + 109051904);
        u16* mk16  = (u16*)(ws + 117440512);            // [4096][4096]; memT later
        u16* sc16  = (u16*)(ws + 150994944);
        u16* pr    = (u16*)(ws + 155189248);
        u16* mt    = mk16;
        u32* flag  = (u32*)sc16;                        // free until scores GEMM

        cvt_all<<<dim3(4096), blk, 0, stream>>>(memory, inputs, wq, wk,
                                                mem16, in16, wq16, wk16, flag);

        // mk on the 4-deep-ring 256^2 kernel: 256 blocks = 1/CU
        gemm8ph<<<dim3(256), dim3(512), 131072, stream>>>(mem16, wk16, mk16);

        vfy_mk<<<dim3(64), blk, 0, stream>>>(mem16, wk16, mk16, flag);
        proj_redo<<<dim3(32, 32, 1), blk, 0, stream>>>(flag, mem16, wk16, mk16);

        // xq on verified 128^2 path (256 blocks)
        gemm_b16<0><<<dim3(32, 8, 1), blk, 0, stream>>>(in16, wq16, xq16, 4096, 4096,
                                                        0L, 0L, 0L, 1.0f);
        // scores on 64x128 tiles: 256 blocks (overwrites flag region — after redo)
        gemm64<<<dim3(16, 8, 2), blk, 0, stream>>>(xq16, mk16, sc16, 4096, 2048,
                                                   512L*4096, 2048L*4096, 512L*2048,
                                                   0.015625f);
        softmax_argmax16<<<dim3(1024), blk, 0, stream>>>(sc16, pr, out, seg);

        transpose_u16<<<dim3(64, 32, 2), blk, 0, stream>>>(mem16, mt);
        gemm_b16<1><<<dim3(32, 4, 2), blk, 0, stream>>>(pr, mt, out, 2048, 4096,
                                                        512L*2048, 4096L*2048, 512L*4096,
                                                        1.0f);
    } else {
        // ---------------- FALLBACK: R10 (passing) ----------------
        u16* xq16 = (u16*)(ws);
        u16* mk16 = (u16*)(ws + (8u<<20));
        u16* sc16 = (u16*)(ws + (24u<<20));
        u16* pr   = (u16*)(ws + (28u<<20));

        gemm_bt<1,0><<<dim3(32, 8, 1), blk, 0, stream>>>(inputs, wq, xq16, 4096, 4096, 1.0f);
        for (int b = 0; b < 2; ++b){
            const float* memb = memory + (size_t)b * 2048 * 4096;
            gemm_bt<1,0><<<dim3(32, 16, 1), blk, 0, stream>>>(memb, wk, mk16, 4096, 4096, 1.0f);
            gemm_bt<0,0><<<dim3(16, 4, 1), blk, 0, stream>>>(xq16 + (size_t)b*512*4096, mk16,
                                                             sc16 + (size_t)b*512*2048,
                                                             4096, 2048, 0.015625f);
        }
        softmax_argmax16<<<dim3(1024), blk, 0, stream>>>(sc16, pr, out, seg);
        for (int b = 0; b < 2; ++b){
            const float* memb = memory + (size_t)b * 2048 * 4096;
            transpose_f2b<<<dim3(64, 32, 1), blk, 0, stream>>>(memb, mk16);
            gemm_bt<0,1><<<dim3(32, 4, 1), blk, 0, stream>>>(pr + (size_t)b*512*2048, mk16,
                                                             out + (size_t)b*512*4096,
                                                             2048, 4096, 1.0f);
        }
    }
}